// Round 9
// baseline (309.286 us; speedup 1.0000x reference)
//
#include <hip/hip_runtime.h>
#include <cstdint>
#include <cstddef>

// BitLlamaAttention: B=1, S=2048, HIDDEN=2048, NH=16, HD=128, GROUP=128
// r18: flash quarter-split for occupancy. r15 profile: flash Occupancy
// 18.6% = 2 blocks/CU while LDS(40KB)+VGPR(128) allow exactly 4.  New grid:
// 1024 blocks = (pair p, h, zq in 0..3); each block runs quarter zq of legs
// qt=31-p and qt=p (~8.25 jt, uniform) -> 4 blocks/CU, 2x wave pool.
// 4 O-partials, workspace flat via aliasing: O2=wqkv_q (dead post-qkv),
// O3=scr16 (x_bf slot, dead post-qkv), attn=wqkv tail.  Combine merges 4
// partials with l>0 guards (skips empty-quarter loads; avoids 0*NaN on
// aliased garbage).  gemm_qkv/gemm_wo/quant/rope/vtrans frozen at r17.

typedef __attribute__((ext_vector_type(8))) short bf16x8;
typedef __attribute__((ext_vector_type(4))) float f32x4;
typedef __attribute__((address_space(3))) void lds_void;
typedef const __attribute__((address_space(1))) void gmem_void;

__device__ __forceinline__ short f2bf(float x) {
    union { float f; uint32_t u; } c; c.f = x;
    uint32_t r = (c.u + 0x7FFFu + ((c.u >> 16) & 1u)) >> 16;
    return (short)r;
}
__device__ __forceinline__ float bf2f(short x) {
    union { uint32_t u; float f; } c; c.u = ((uint32_t)(uint16_t)x) << 16;
    return c.f;
}

// ------------------------------------------------------------ dtype probe
__global__ __launch_bounds__(64) void zero_flag(int* f) {
    if (threadIdx.x == 0) *f = 0;
}

__global__ __launch_bounds__(256) void detect_kernel(
    const unsigned short* __restrict__ p, int n, int* __restrict__ flag)
{
    int tid = blockIdx.x * 256 + threadIdx.x;
    int cnt = 0;
    for (int i = tid; i < n; i += 65536) {
        int e = (p[i] >> 7) & 0xFF;
        cnt += (e >= 0xF0) ? 1 : 0;
    }
#pragma unroll
    for (int off = 1; off < 64; off <<= 1) cnt += __shfl_xor(cnt, off);
    if ((threadIdx.x & 63) == 0 && cnt) atomicAdd(flag, cnt);
}

// canonicalize hidden_states to bf16, 4 elems/thread
__global__ __launch_bounds__(256) void convert_kernel(
    const void* __restrict__ in, short* __restrict__ out, int n,
    const int* __restrict__ flag)
{
    bool isf32 = (*flag > 1000);
    int i = (blockIdx.x * 256 + threadIdx.x) * 4;
    if (i >= n) return;
    if (isf32) {
        float4 v = *(const float4*)((const float*)in + i);
        short4 o;
        o.x = f2bf(v.x); o.y = f2bf(v.y); o.z = f2bf(v.z); o.w = f2bf(v.w);
        *(short4*)(out + i) = o;
    } else {
        *(short4*)(out + i) = *(const short4*)((const short*)in + i);
    }
}

// ---------------------------------------------------------------- quantize
// 4 elems/thread (16B f32 loads), group=128 elems=32 lanes, 5-round reduce.
__global__ __launch_bounds__(256) void quant_kernel(
    const void* __restrict__ w0, const void* __restrict__ w1,
    const void* __restrict__ w2, const void* __restrict__ w3,
    short* __restrict__ q0, short* __restrict__ q1,
    short* __restrict__ q2, short* __restrict__ q3,
    const int* __restrict__ flag)
{
    bool isf32 = (*flag > 1000);
    int t   = blockIdx.x * 256 + threadIdx.x;      // 4M threads
    int mat = t >> 20;                             // 1M threads per matrix
    int e4  = t & 1048575;                         // quad index in matrix
    const void* w = (mat == 0) ? w0 : (mat == 1) ? w1 : (mat == 2) ? w2 : w3;
    short*      q = (mat == 0) ? q0 : (mat == 1) ? q1 : (mat == 2) ? q2 : q3;
    float a0, a1, a2, a3;
    if (isf32) {
        float4 v = *(const float4*)((const float*)w + (long long)e4 * 4);
        a0 = v.x; a1 = v.y; a2 = v.z; a3 = v.w;
    } else {
        short4 v = *(const short4*)((const short*)w + (long long)e4 * 4);
        a0 = bf2f(v.x); a1 = bf2f(v.y); a2 = bf2f(v.z); a3 = bf2f(v.w);
    }
    float s = fabsf(a0) + fabsf(a1) + fabsf(a2) + fabsf(a3);
#pragma unroll
    for (int off = 1; off < 32; off <<= 1) s += __shfl_xor(s, off);
    float scale = fmaxf(s * (1.0f / 128.0f), 1e-8f);
    float inv = 1.0f / scale;
    auto qz = [&](float a) -> short {
        float na = a * inv;
        return f2bf((na > 0.5f) ? scale : (na < -0.5f) ? -scale : 0.0f);
    };
    short4 o;
    o.x = qz(a0); o.y = qz(a1); o.z = qz(a2); o.w = qz(a3);
    *(short4*)(q + (long long)e4 * 4) = o;
}

// ---------------------------------------------------------------- QKV GEMM
// C[2048][6144] = x_bf[2048x2048] @ wqkv^T[6144x2048].  128x192 tiles,
// BK=32, grid(32,16) = 512 blocks = 2/CU.  4 waves (2Mx2N), per-wave
// 64x96 = 4m x 6n frags.  Triple-buffered LDS, 2-deep prefetch, counted
// vmcnt(5) boundary (5 loads/thread/tile: 2 A + 3 B).  [r11, 61.6us]
__global__ __launch_bounds__(256, 2) void gemm_qkv(
    const short* __restrict__ A, const short* __restrict__ B,
    short* __restrict__ C)
{
    __shared__ short lds[30720];                   // 60 KiB = 3 x (8K A + 12K B)

    int wg = blockIdx.y * 32 + blockIdx.x;         // 512 wgs, 512%8==0
    int sw = (wg & 7) * 64 + (wg >> 3);            // XCD-contiguous chunks
    int bx = sw & 31, by = sw >> 5;

    const short* Ab = A + (long long)by * 128 * 2048;
    const short* Bb = B + (long long)bx * 192 * 2048;

    int tid = threadIdx.x, lane = tid & 63, wid = tid >> 6;
    int wr = wid >> 1, wc = wid & 1;               // wave grid 2x2
    int quad = lane >> 4, lm = lane & 15;

    f32x4 acc[4][6];
#pragma unroll
    for (int i = 0; i < 4; i++)
#pragma unroll
        for (int j = 0; j < 6; j++)
#pragma unroll
            for (int r = 0; r < 4; r++) acc[i][j][r] = 0.0f;

    auto stage = [&](int tn, short* buf) {
        short* dA = buf;                           // 4096 shorts
        short* dB = buf + 4096;                    // 6144 shorts
#pragma unroll
        for (int l = 0; l < 2; l++) {
            int ci  = l * 256 + tid;               // 512 chunks of 16B
            int row = ci >> 2;
            int kc  = ((ci & 3) - (row >> 1)) & 3; // inverse swizzle on src
            const short* gp = Ab + (long long)row * 2048 + tn * 32 + kc * 8;
            __builtin_amdgcn_global_load_lds((gmem_void*)gp, (lds_void*)(dA + ci * 8), 16, 0, 0);
        }
#pragma unroll
        for (int l = 0; l < 3; l++) {
            int ci  = l * 256 + tid;               // 768 chunks of 16B
            int row = ci >> 2;
            int kc  = ((ci & 3) - (row >> 1)) & 3;
            const short* gp = Bb + (long long)row * 2048 + tn * 32 + kc * 8;
            __builtin_amdgcn_global_load_lds((gmem_void*)gp, (lds_void*)(dB + ci * 8), 16, 0, 0);
        }
    };

    auto tile = [&](short* cur, short* nxt, int tn, bool pf) {
        if (pf) stage(tn, nxt);                    // issue-early prefetch
        short* cA = cur;
        short* cB = cur + 4096;
        bf16x8 af[4], bg[6];
        // phase 0: all A frags + B n0-2, 12 MFMA
#pragma unroll
        for (int m = 0; m < 4; m++) {
            int R = wr * 64 + m * 16 + lm;
            af[m] = *(const bf16x8*)(cA + R * 32 + (((quad + (R >> 1)) & 3) << 3));
        }
#pragma unroll
        for (int n = 0; n < 3; n++) {
            int R = wc * 96 + n * 16 + lm;
            bg[n] = *(const bf16x8*)(cB + R * 32 + (((quad + (R >> 1)) & 3) << 3));
        }
        __builtin_amdgcn_s_setprio(1);
#pragma unroll
        for (int m = 0; m < 4; m++)
#pragma unroll
            for (int n = 0; n < 3; n++)
                acc[m][n] = __builtin_amdgcn_mfma_f32_16x16x32_bf16(af[m], bg[n], acc[m][n], 0, 0, 0);
        __builtin_amdgcn_s_setprio(0);
        // phase 1: B n3-5, 12 MFMA
#pragma unroll
        for (int n = 3; n < 6; n++) {
            int R = wc * 96 + n * 16 + lm;
            bg[n] = *(const bf16x8*)(cB + R * 32 + (((quad + (R >> 1)) & 3) << 3));
        }
        __builtin_amdgcn_s_setprio(1);
#pragma unroll
        for (int m = 0; m < 4; m++)
#pragma unroll
            for (int n = 3; n < 6; n++)
                acc[m][n] = __builtin_amdgcn_mfma_f32_16x16x32_bf16(af[m], bg[n], acc[m][n], 0, 0, 0);
        __builtin_amdgcn_s_setprio(0);
        // boundary: tile tn-1 (oldest 5 loads) must be resident; keep the
        // newest 5 (tile tn) in flight.  Only the final 2 iters drain.
        if (pf) asm volatile("s_waitcnt vmcnt(5)" ::: "memory");
        else    asm volatile("s_waitcnt vmcnt(0)" ::: "memory");
        __builtin_amdgcn_s_barrier();
    };

    short* c0 = lds;
    short* c1 = lds + 10240;
    short* c2 = lds + 20480;
    stage(0, c0);
    stage(1, c1);
    asm volatile("s_waitcnt vmcnt(5)" ::: "memory");   // tile 0 resident
    __builtin_amdgcn_s_barrier();

    for (int t = 0; t < 64; t++) {
        tile(c0, c2, t + 2, t + 2 < 64);
        short* tmp = c0; c0 = c1; c1 = c2; c2 = tmp;
    }

    // epilogue: row-major bf16
#pragma unroll
    for (int m = 0; m < 4; m++)
#pragma unroll
        for (int n = 0; n < 6; n++)
#pragma unroll
            for (int r = 0; r < 4; r++) {
                int row = by * 128 + wr * 64 + m * 16 + quad * 4 + r;
                int col = bx * 192 + wc * 96 + n * 16 + lm;
                C[(long long)row * 6144 + col] = f2bf(acc[m][n][r]);
            }
}

// ------------------------------------------------------------ V transpose
// v_t[o][t] = qkv[t][4096+o].  64x64 tiles through LDS, chunk-xor swizzle.
__global__ __launch_bounds__(256) void vtrans_kernel(
    const short* __restrict__ qkv, short* __restrict__ v_t)
{
    __shared__ short lt[4096];
    int bt = blockIdx.x, bo = blockIdx.y;
    int tid = threadIdx.x;
    int r = tid >> 3, c = tid & 7;
#pragma unroll
    for (int h = 0; h < 2; h++) {
        int row = h * 32 + r;                      // t-local
        bf16x8 v = *(const bf16x8*)(qkv + (long long)(bt * 64 + row) * 6144 + 4096 + bo * 64 + c * 8);
        *(bf16x8*)(lt + row * 64 + ((c ^ (row & 7)) << 3)) = v;
    }
    __syncthreads();
#pragma unroll
    for (int h = 0; h < 2; h++) {
        int o = h * 32 + r;                        // o-local
        bf16x8 ov;
#pragma unroll
        for (int k = 0; k < 8; k++) {
            int row = c * 8 + k;
            ov[k] = lt[row * 64 + ((((o >> 3) ^ (row & 7))) << 3) + (o & 7)];
        }
        *(bf16x8*)(v_t + (long long)(bo * 64 + o) * 2048 + bt * 64 + c * 8) = ov;
    }
}

// ---------------------------------------------------------------- WO GEMM
// d_out[2048][2048] fp32 = attn bf16 @ wo_q^T.  128x64 tiles, BK=32,
// grid(32,16) = 512 = 2/CU.  4 waves (2Mx2N), per-wave 64x32 = 4m x 2n.
// Triple-buffered LDS (36 KB), 2-deep prefetch, counted vmcnt(3).
__global__ __launch_bounds__(256, 2) void gemm_wo(
    const short* __restrict__ A, const short* __restrict__ B,
    float* __restrict__ C)
{
    __shared__ short lds[18432];                   // 36 KiB = 3 x (8K A + 4K B)

    int wg = blockIdx.y * 32 + blockIdx.x;         // 512 wgs
    int sw = (wg & 7) * 64 + (wg >> 3);            // XCD-contiguous
    int bx = sw & 31, by = sw >> 5;

    const short* Ab = A + (long long)by * 128 * 2048;
    const short* Bb = B + (long long)bx * 64 * 2048;

    int tid = threadIdx.x, lane = tid & 63, wid = tid >> 6;
    int wr = wid >> 1, wc = wid & 1;               // wave grid 2x2
    int quad = lane >> 4, lm = lane & 15;

    f32x4 acc[4][2];
#pragma unroll
    for (int i = 0; i < 4; i++)
#pragma unroll
        for (int j = 0; j < 2; j++)
#pragma unroll
            for (int r = 0; r < 4; r++) acc[i][j][r] = 0.0f;

    auto stage = [&](int tn, short* buf) {
        short* dA = buf;                           // 4096 shorts (512 chunks)
        short* dB = buf + 4096;                    // 2048 shorts (256 chunks)
#pragma unroll
        for (int l = 0; l < 2; l++) {
            int ci  = l * 256 + tid;
            int row = ci >> 2;
            int kc  = ((ci & 3) - (row >> 1)) & 3;
            const short* gp = Ab + (long long)row * 2048 + tn * 32 + kc * 8;
            __builtin_amdgcn_global_load_lds((gmem_void*)gp, (lds_void*)(dA + ci * 8), 16, 0, 0);
        }
        {
            int ci  = tid;
            int row = ci >> 2;
            int kc  = ((ci & 3) - (row >> 1)) & 3;
            const short* gp = Bb + (long long)row * 2048 + tn * 32 + kc * 8;
            __builtin_amdgcn_global_load_lds((gmem_void*)gp, (lds_void*)(dB + ci * 8), 16, 0, 0);
        }
    };

    auto tile = [&](short* cur, short* nxt, int tn, bool pf) {
        if (pf) stage(tn, nxt);
        short* cA = cur;
        short* cB = cur + 4096;
        bf16x8 af[4], bg[2];
#pragma unroll
        for (int m = 0; m < 4; m++) {
            int R = wr * 64 + m * 16 + lm;
            af[m] = *(const bf16x8*)(cA + R * 32 + (((quad + (R >> 1)) & 3) << 3));
        }
#pragma unroll
        for (int n = 0; n < 2; n++) {
            int R = wc * 32 + n * 16 + lm;
            bg[n] = *(const bf16x8*)(cB + R * 32 + (((quad + (R >> 1)) & 3) << 3));
        }
        __builtin_amdgcn_s_setprio(1);
#pragma unroll
        for (int m = 0; m < 4; m++)
#pragma unroll
            for (int n = 0; n < 2; n++)
                acc[m][n] = __builtin_amdgcn_mfma_f32_16x16x32_bf16(af[m], bg[n], acc[m][n], 0, 0, 0);
        __builtin_amdgcn_s_setprio(0);
        if (pf) asm volatile("s_waitcnt vmcnt(3)" ::: "memory");
        else    asm volatile("s_waitcnt vmcnt(0)" ::: "memory");
        __builtin_amdgcn_s_barrier();
    };

    short* c0 = lds;
    short* c1 = lds + 6144;
    short* c2 = lds + 12288;
    stage(0, c0);
    stage(1, c1);
    asm volatile("s_waitcnt vmcnt(3)" ::: "memory");
    __builtin_amdgcn_s_barrier();

    for (int t = 0; t < 64; t++) {
        tile(c0, c2, t + 2, t + 2 < 64);
        short* tmp = c0; c0 = c1; c1 = c2; c2 = tmp;
    }

    // epilogue: fp32 row-major
#pragma unroll
    for (int m = 0; m < 4; m++)
#pragma unroll
        for (int n = 0; n < 2; n++)
#pragma unroll
            for (int r = 0; r < 4; r++) {
                int row = by * 128 + wr * 64 + m * 16 + quad * 4 + r;
                int col = bx * 64 + wc * 32 + n * 16 + lm;
                C[(long long)row * 2048 + col] = acc[m][n][r];
            }
}

// ---------------------------------------------------------------- RoPE
// reads qkv[2048][6144] (q cols 0..2047, k cols 2048..4095), bf16x8 vec.
// Q pre-scaled by SC*log2e so flash scores are in log2 units (exp2 native).
__global__ __launch_bounds__(256) void rope_kernel(
    const short* __restrict__ qk,
    short* __restrict__ qr, short* __restrict__ kr)
{
    const float QSC = 0.1275174150637756f;         // (1/sqrt(128))*log2(e)
    int idx = blockIdx.x * 256 + threadIdx.x;
    int d8 = (idx & 7) * 8;
    int h  = (idx >> 3) & 15;
    int s  = idx >> 7;
    long long io = (long long)s * 6144 + h * 128 + d8;
    long long oo = (long long)h * 262144 + (long long)s * 128 + d8;
    bf16x8 x1q = *(const bf16x8*)(qk + io);
    bf16x8 x2q = *(const bf16x8*)(qk + io + 64);
    bf16x8 x1k = *(const bf16x8*)(qk + io + 2048);
    bf16x8 x2k = *(const bf16x8*)(qk + io + 2112);
    bf16x8 o1q, o2q, o1k, o2k;
#pragma unroll
    for (int j = 0; j < 8; j++) {
        float inv = exp2f((float)(d8 + j) * -0.20762050593261719f);
        float ang = (float)s * inv;
        float sn, c;
        sincosf(ang, &sn, &c);
        float a1 = bf2f(x1q[j]), a2 = bf2f(x2q[j]);
        o1q[j] = f2bf((a1 * c - a2 * sn) * QSC);
        o2q[j] = f2bf((a1 * sn + a2 * c) * QSC);
        float b1 = bf2f(x1k[j]), b2 = bf2f(x2k[j]);
        o1k[j] = f2bf(b1 * c - b2 * sn);
        o2k[j] = f2bf(b1 * sn + b2 * c);
    }
    *(bf16x8*)(qr + oo)      = o1q;
    *(bf16x8*)(qr + oo + 64) = o2q;
    *(bf16x8*)(kr + oo)      = o1k;
    *(bf16x8*)(kr + oo + 64) = o2k;
}

// ---------------------------------------------------------------- flash attn
// 1024 blocks: zq = bid&3 (j-quarter), h = (bid>>2)&15, p = bid>>6 (0..15).
// Each block: quarter zq of leg qt=31-p, then quarter zq of leg qt=p
// (~8.25 jt, uniform).  4 blocks/CU (LDS 40960 x4 = 160KiB exactly;
// launch_bounds(256,4) pins VGPR<=128).  Scores in log2 units; per-lane
// partial l (reduced per leg); vote-gated max (THR=11.5 ~ e^8); setprio.
// Empty quarters write m=-1e30,l=0 and skip O (combine guards on l>0).
__global__ __launch_bounds__(256, 4) void flash_kernel(
    const short* __restrict__ q_r, const short* __restrict__ k_r,
    const short* __restrict__ v_t,
    float* __restrict__ O0, float* __restrict__ O1,
    float* __restrict__ O2, float* __restrict__ O3,
    float* __restrict__ mpart, float* __restrict__ lpart)
{
    const float THR = 11.5f;
    int bid = blockIdx.x;
    int zq = bid & 3;
    int h  = (bid >> 2) & 15;
    int p  = bid >> 6;

    int tid = threadIdx.x, lane = tid & 63, wv = tid >> 6;
    int quad = lane >> 4, lm = lane & 15;

    __shared__ short lK[64 * 128];
    __shared__ short lV[128 * 64];
    __shared__ short lP[64 * 64];

    const short* kb = k_r + h * 262144;
    const short* vb = v_t + h * 128 * 2048;
    float* Ob = (zq == 0) ? O0 : (zq == 1) ? O1 : (zq == 2) ? O2 : O3;

    for (int leg = 0; leg < 2; leg++) {
        int qt = leg ? p : 31 - p;
        int n  = qt + 1;
        int jb = (n * zq) >> 2;
        int je = (n * (zq + 1)) >> 2;

        const short* qb = q_r + h * 262144 + (qt * 64 + wv * 16) * 128;
        bf16x8 aq[4];
#pragma unroll
        for (int kc = 0; kc < 4; kc++)
            aq[kc] = *(const bf16x8*)(qb + lm * 128 + kc * 32 + quad * 8);

        f32x4 ao[8];
#pragma unroll
        for (int nt = 0; nt < 8; nt++)
#pragma unroll
            for (int r = 0; r < 4; r++) ao[nt][r] = 0.0f;
        float mrow[4], lrow[4];                    // lrow = PER-LANE partial
#pragma unroll
        for (int r = 0; r < 4; r++) { mrow[r] = -1e30f; lrow[r] = 0.0f; }

        if (jb < je) {
#pragma unroll
            for (int i = 0; i < 4; i++) {
                int ci = i * 256 + tid;
                int r = ci >> 4, cp = ci & 15;
                int c = (cp & 8) | ((cp & 7) ^ (r & 7));
                const short* gp = kb + (jb * 64 + r) * 128 + c * 8;
                __builtin_amdgcn_global_load_lds((gmem_void*)gp, (lds_void*)(lK + ci * 8), 16, 0, 0);
            }
        }
        __syncthreads();

        for (int jt = jb; jt < je; jt++) {
#pragma unroll
            for (int i = 0; i < 4; i++) {
                int ci = i * 256 + tid;
                int r = ci >> 3, cp = ci & 7;
                int c = cp ^ (r & 7);
                const short* gp = vb + r * 2048 + jt * 64 + c * 8;
                __builtin_amdgcn_global_load_lds((gmem_void*)gp, (lds_void*)(lV + ci * 8), 16, 0, 0);
            }
            f32x4 as[4];
#pragma unroll
            for (int nt = 0; nt < 4; nt++)
#pragma unroll
                for (int r = 0; r < 4; r++) as[nt][r] = 0.0f;
            __builtin_amdgcn_s_setprio(1);
#pragma unroll
            for (int kc = 0; kc < 4; kc++) {
#pragma unroll
                for (int nt = 0; nt < 4; nt++) {
                    int r = nt * 16 + lm;
                    int c = kc * 4 + quad;
                    int slot = (c & 8) | ((c & 7) ^ (r & 7));
                    bf16x8 bk = *(const bf16x8*)(lK + (r * 16 + slot) * 8);
                    as[nt] = __builtin_amdgcn_mfma_f32_16x16x32_bf16(aq[kc], bk, as[nt], 0, 0, 0);
                }
            }
            __builtin_amdgcn_s_setprio(0);
            if (jt == qt) {                        // diag mask only
#pragma unroll
                for (int nt = 0; nt < 4; nt++)
#pragma unroll
                    for (int r = 0; r < 4; r++) {
                        int qg = wv * 16 + quad * 4 + r;
                        int tg = nt * 16 + lm;
                        if (tg > qg) as[nt][r] = -1e30f;
                    }
            }
#pragma unroll
            for (int r = 0; r < 4; r++) {
                float lmax = fmaxf(fmaxf(as[0][r], as[1][r]), fmaxf(as[2][r], as[3][r]));
                if (__any(lmax > mrow[r] + THR)) {
                    float mx = lmax;
#pragma unroll
                    for (int off = 1; off < 16; off <<= 1) mx = fmaxf(mx, __shfl_xor(mx, off));
                    if (mx > mrow[r] + THR) {
                        float alpha = exp2f(mrow[r] - mx);   // group-uniform
                        lrow[r] *= alpha;
#pragma unroll
                        for (int nt = 0; nt < 8; nt++) ao[nt][r] *= alpha;
                        mrow[r] = mx;
                    }
                }
                float ps = 0.0f;
#pragma unroll
                for (int nt = 0; nt < 4; nt++) {
                    float pv = exp2f(as[nt][r] - mrow[r]);
                    as[nt][r] = pv;
                    ps += pv;
                }
                lrow[r] += ps;                     // per-lane partial
                int row = wv * 16 + quad * 4 + r;
#pragma unroll
                for (int nt = 0; nt < 4; nt++) {
                    int slot = (nt * 2 + (lm >> 3) + 2 * quad) & 7;   // uniform
                    lP[row * 64 + slot * 8 + (lm & 7)] = f2bf(as[nt][r]);
                }
            }
            __syncthreads();
            if (jt + 1 < je) {
#pragma unroll
                for (int i = 0; i < 4; i++) {
                    int ci = i * 256 + tid;
                    int r = ci >> 4, cp = ci & 15;
                    int c = (cp & 8) | ((cp & 7) ^ (r & 7));
                    const short* gp = kb + ((jt + 1) * 64 + r) * 128 + c * 8;
                    __builtin_amdgcn_global_load_lds((gmem_void*)gp, (lds_void*)(lK + ci * 8), 16, 0, 0);
                }
            }
            __builtin_amdgcn_s_setprio(1);
#pragma unroll
            for (int kt = 0; kt < 2; kt++) {
                int prow = wv * 16 + lm;
                int slot = (kt * 4 + quad + 2 * (lm >> 2)) & 7;       // matches write
                bf16x8 ap = *(const bf16x8*)(lP + prow * 64 + slot * 8);
#pragma unroll
                for (int nt = 0; nt < 8; nt++) {
                    int r = nt * 16 + lm;
                    int c = kt * 4 + quad;
                    int vslot = c ^ (r & 7);
                    bf16x8 bv = *(const bf16x8*)(lV + (r * 8 + vslot) * 8);
                    ao[nt] = __builtin_amdgcn_mfma_f32_16x16x32_bf16(ap, bv, ao[nt], 0, 0, 0);
                }
            }
            __builtin_amdgcn_s_setprio(0);
            __syncthreads();
        }

        // leg epilogue: reduce per-lane l partials (16-wide), store.
#pragma unroll
        for (int r = 0; r < 4; r++) {
            float l = lrow[r];
#pragma unroll
            for (int off = 1; off < 16; off <<= 1) l += __shfl_xor(l, off);
            int sg = qt * 64 + wv * 16 + quad * 4 + r;
            if (jb < je) {
#pragma unroll
                for (int nt = 0; nt < 8; nt++) {
                    int dg = h * 128 + nt * 16 + lm;
                    Ob[(long long)sg * 2048 + dg] = ao[nt][r];
                }
            }
            if (lm == 0) {
                mpart[zq * 32768 + h * 2048 + sg] = mrow[r];   // log2 units
                lpart[zq * 32768 + h * 2048 + sg] = l;
            }
        }
    }
}

// ---------------------------------------------------------------- combine
// 4 partials, m in log2 units.  l>0 guards skip empty quarters (and avoid
// reading aliased-garbage O which may contain NaN).
__global__ __launch_bounds__(256) void combine_kernel(
    const float* __restrict__ O0, const float* __restrict__ O1,
    const float* __restrict__ O2, const float* __restrict__ O3,
    const float* __restrict__ mpart, const float* __restrict__ lpart,
    short* __restrict__ attn)
{
    int idx = blockIdx.x * 256 + threadIdx.x;   // 1M threads
    int e = idx * 4;
    int s = e >> 11, h = (e & 2047) >> 7;
    float m[4], l[4];
#pragma unroll
    for (int i = 0; i < 4; i++) {
        m[i] = mpart[i * 32768 + h * 2048 + s];
        l[i] = lpart[i * 32768 + h * 2048 + s];
    }
    float M = fmaxf(fmaxf(m[0], m[1]), fmaxf(m[2], m[3]));
    const float* Os[4] = { O0, O1, O2, O3 };
    float den = 0.0f, ax = 0.0f, ay = 0.0f, az = 0.0f, aw = 0.0f;
#pragma unroll
    for (int i = 0; i < 4; i++) {
        if (l[i] > 0.0f) {
            float w = exp2f(m[i] - M);
            float4 a = *(const float4*)(Os[i] + e);
            ax += a.x * w; ay += a.y * w; az += a.z * w; aw += a.w * w;
            den += l[i] * w;
        }
    }
    float inv = 1.0f / den;
    short4 o;
    o.x = f2bf(ax * inv);
    o.y = f2bf(ay * inv);
    o.z = f2bf(az * inv);
    o.w = f2bf(aw * inv);
    *(short4*)(attn + e) = o;
}

// ---------------------------------------------------------------- launch
extern "C" void kernel_launch(void* const* d_in, const int* in_sizes, int n_in,
                              void* d_out, int out_size, void* d_ws, size_t ws_size,
                              hipStream_t stream)
{
    const void* x  = d_in[0];
    const void* wq = d_in[2];
    const void* wk = d_in[3];
    const void* wv = d_in[4];
    const void* wo = d_in[5];

    char* ws = (char*)d_ws;
    size_t off = 0;
    auto alloc = [&](size_t b) { void* p = ws + off; off += (b + 255) & ~(size_t)255; return p; };
    short* wqkv_q = (short*)alloc(25165824);   // [6144][2048] bf16; dead post-qkv
    short* wo_q   = (short*)alloc(8388608);
    float* Op01   = (float*)alloc(33554432);   // O0,O1; aliases qkv pre-flash
    short* qkv    = (short*)Op01;              // [2048][6144] bf16
    short* v_t    = (short*)alloc(8388608);    // [o][t]
    short* q_r    = (short*)alloc(8388608);    // [h][s][128]
    short* k_r    = (short*)alloc(8388608);
    char*  scr16  = (char*)alloc(16777216);    // x_bf (first half) pre-qkv; O3 post
    short* x_bf   = (short*)scr16;
    float* mpart  = (float*)alloc(524288);     // [4][16][2048]
    float* lpart  = (float*)alloc(524288);
    int*   flag   = (int*)alloc(256);
    if (off > ws_size) return;                 // ~111 MB

    float* O0 = Op01;
    float* O1 = Op01 + 4194304;
    float* O2 = (float*)wqkv_q;                // wqkv dead after gemm_qkv
    float* O3 = (float*)scr16;                 // x_bf dead after gemm_qkv
    short* attn = (short*)((char*)wqkv_q + 16777216);   // wqkv tail (8.39MB)

    zero_flag<<<1, 64, 0, stream>>>(flag);
    detect_kernel<<<256, 256, 0, stream>>>(
        (const unsigned short*)x, in_sizes[0], flag);
    convert_kernel<<<4096, 256, 0, stream>>>(x, x_bf, 4194304, flag);

    quant_kernel<<<16384, 256, 0, stream>>>(wq, wk, wv, wo,
        wqkv_q, wqkv_q + 4194304, wqkv_q + 8388608, wo_q, flag);

    gemm_qkv<<<dim3(32, 16), 256, 0, stream>>>(x_bf, wqkv_q, qkv);

    rope_kernel<<<1024, 256, 0, stream>>>(qkv, q_r, k_r);
    vtrans_kernel<<<dim3(32, 32), 256, 0, stream>>>(qkv, v_t);

    flash_kernel<<<1024, 256, 0, stream>>>(q_r, k_r, v_t,
        O0, O1, O2, O3, mpart, lpart);
    combine_kernel<<<4096, 256, 0, stream>>>(
        O0, O1, O2, O3, mpart, lpart, attn);

    gemm_wo<<<dim3(32, 16), 256, 0, stream>>>(attn, wo_q, (float*)d_out);
}

// Round 10
// 296.904 us; speedup vs baseline: 1.0417x; 1.0417x over previous
//
#include <hip/hip_runtime.h>
#include <cstdint>
#include <cstddef>

// BitLlamaAttention: B=1, S=2048, HIDDEN=2048, NH=16, HD=128, GROUP=128
// r19: r18 quarter-split REVERTED (309.3 vs r17's 306.1; 1.9x O-write +
// heavier combine ate the occupancy gain). Base = r17 exactly, plus:
//  1) gemm_qkv XCD swizzle flipped to B-locality: bx=sw>>4, by=sw&15.
//     Old mapping: each XCD held 2 A-panels (1MB, L2-fits) but ALL 32
//     B-columns (24.6MB >> 4MB L2) -> B re-fetch = FETCH 134MB vs 60 ideal.
//     New: each XCD owns 4 bx-columns (B slice 3MB, L2-resident); A via L3.
//  2) rope+vtrans fused into one 2048-block launch (disjoint reads of qkv,
//     disjoint outputs, no ordering) - one less launch, tails overlap.

typedef __attribute__((ext_vector_type(8))) short bf16x8;
typedef __attribute__((ext_vector_type(4))) float f32x4;
typedef __attribute__((address_space(3))) void lds_void;
typedef const __attribute__((address_space(1))) void gmem_void;

__device__ __forceinline__ short f2bf(float x) {
    union { float f; uint32_t u; } c; c.f = x;
    uint32_t r = (c.u + 0x7FFFu + ((c.u >> 16) & 1u)) >> 16;
    return (short)r;
}
__device__ __forceinline__ float bf2f(short x) {
    union { uint32_t u; float f; } c; c.u = ((uint32_t)(uint16_t)x) << 16;
    return c.f;
}

// ------------------------------------------------------------ dtype probe
__global__ __launch_bounds__(64) void zero_flag(int* f) {
    if (threadIdx.x == 0) *f = 0;
}

__global__ __launch_bounds__(256) void detect_kernel(
    const unsigned short* __restrict__ p, int n, int* __restrict__ flag)
{
    int tid = blockIdx.x * 256 + threadIdx.x;
    int cnt = 0;
    for (int i = tid; i < n; i += 65536) {
        int e = (p[i] >> 7) & 0xFF;
        cnt += (e >= 0xF0) ? 1 : 0;
    }
#pragma unroll
    for (int off = 1; off < 64; off <<= 1) cnt += __shfl_xor(cnt, off);
    if ((threadIdx.x & 63) == 0 && cnt) atomicAdd(flag, cnt);
}

// canonicalize hidden_states to bf16, 4 elems/thread
__global__ __launch_bounds__(256) void convert_kernel(
    const void* __restrict__ in, short* __restrict__ out, int n,
    const int* __restrict__ flag)
{
    bool isf32 = (*flag > 1000);
    int i = (blockIdx.x * 256 + threadIdx.x) * 4;
    if (i >= n) return;
    if (isf32) {
        float4 v = *(const float4*)((const float*)in + i);
        short4 o;
        o.x = f2bf(v.x); o.y = f2bf(v.y); o.z = f2bf(v.z); o.w = f2bf(v.w);
        *(short4*)(out + i) = o;
    } else {
        *(short4*)(out + i) = *(const short4*)((const short*)in + i);
    }
}

// ---------------------------------------------------------------- quantize
// 4 elems/thread (16B f32 loads), group=128 elems=32 lanes, 5-round reduce.
__global__ __launch_bounds__(256) void quant_kernel(
    const void* __restrict__ w0, const void* __restrict__ w1,
    const void* __restrict__ w2, const void* __restrict__ w3,
    short* __restrict__ q0, short* __restrict__ q1,
    short* __restrict__ q2, short* __restrict__ q3,
    const int* __restrict__ flag)
{
    bool isf32 = (*flag > 1000);
    int t   = blockIdx.x * 256 + threadIdx.x;      // 4M threads
    int mat = t >> 20;                             // 1M threads per matrix
    int e4  = t & 1048575;                         // quad index in matrix
    const void* w = (mat == 0) ? w0 : (mat == 1) ? w1 : (mat == 2) ? w2 : w3;
    short*      q = (mat == 0) ? q0 : (mat == 1) ? q1 : (mat == 2) ? q2 : q3;
    float a0, a1, a2, a3;
    if (isf32) {
        float4 v = *(const float4*)((const float*)w + (long long)e4 * 4);
        a0 = v.x; a1 = v.y; a2 = v.z; a3 = v.w;
    } else {
        short4 v = *(const short4*)((const short*)w + (long long)e4 * 4);
        a0 = bf2f(v.x); a1 = bf2f(v.y); a2 = bf2f(v.z); a3 = bf2f(v.w);
    }
    float s = fabsf(a0) + fabsf(a1) + fabsf(a2) + fabsf(a3);
#pragma unroll
    for (int off = 1; off < 32; off <<= 1) s += __shfl_xor(s, off);
    float scale = fmaxf(s * (1.0f / 128.0f), 1e-8f);
    float inv = 1.0f / scale;
    auto qz = [&](float a) -> short {
        float na = a * inv;
        return f2bf((na > 0.5f) ? scale : (na < -0.5f) ? -scale : 0.0f);
    };
    short4 o;
    o.x = qz(a0); o.y = qz(a1); o.z = qz(a2); o.w = qz(a3);
    *(short4*)(q + (long long)e4 * 4) = o;
}

// ---------------------------------------------------------------- QKV GEMM
// C[2048][6144] = x_bf[2048x2048] @ wqkv^T[6144x2048].  128x192 tiles,
// BK=32, grid(32,16) = 512 blocks = 2/CU.  4 waves (2Mx2N), per-wave
// 64x96 = 4m x 6n frags.  Triple-buffered LDS, 2-deep prefetch, counted
// vmcnt(5).  XCD swizzle: B-locality (each XCD owns 4 bx-cols, 3MB in L2).
__global__ __launch_bounds__(256, 2) void gemm_qkv(
    const short* __restrict__ A, const short* __restrict__ B,
    short* __restrict__ C)
{
    __shared__ short lds[30720];                   // 60 KiB = 3 x (8K A + 12K B)

    int wg = blockIdx.y * 32 + blockIdx.x;         // 512 wgs, 512%8==0
    int sw = (wg & 7) * 64 + (wg >> 3);            // XCD-contiguous chunks
    int bx = sw >> 4, by = sw & 15;                // B-locality: 4 bx/XCD

    const short* Ab = A + (long long)by * 128 * 2048;
    const short* Bb = B + (long long)bx * 192 * 2048;

    int tid = threadIdx.x, lane = tid & 63, wid = tid >> 6;
    int wr = wid >> 1, wc = wid & 1;               // wave grid 2x2
    int quad = lane >> 4, lm = lane & 15;

    f32x4 acc[4][6];
#pragma unroll
    for (int i = 0; i < 4; i++)
#pragma unroll
        for (int j = 0; j < 6; j++)
#pragma unroll
            for (int r = 0; r < 4; r++) acc[i][j][r] = 0.0f;

    auto stage = [&](int tn, short* buf) {
        short* dA = buf;                           // 4096 shorts
        short* dB = buf + 4096;                    // 6144 shorts
#pragma unroll
        for (int l = 0; l < 2; l++) {
            int ci  = l * 256 + tid;               // 512 chunks of 16B
            int row = ci >> 2;
            int kc  = ((ci & 3) - (row >> 1)) & 3; // inverse swizzle on src
            const short* gp = Ab + (long long)row * 2048 + tn * 32 + kc * 8;
            __builtin_amdgcn_global_load_lds((gmem_void*)gp, (lds_void*)(dA + ci * 8), 16, 0, 0);
        }
#pragma unroll
        for (int l = 0; l < 3; l++) {
            int ci  = l * 256 + tid;               // 768 chunks of 16B
            int row = ci >> 2;
            int kc  = ((ci & 3) - (row >> 1)) & 3;
            const short* gp = Bb + (long long)row * 2048 + tn * 32 + kc * 8;
            __builtin_amdgcn_global_load_lds((gmem_void*)gp, (lds_void*)(dB + ci * 8), 16, 0, 0);
        }
    };

    auto tile = [&](short* cur, short* nxt, int tn, bool pf) {
        if (pf) stage(tn, nxt);                    // issue-early prefetch
        short* cA = cur;
        short* cB = cur + 4096;
        bf16x8 af[4], bg[6];
        // phase 0: all A frags + B n0-2, 12 MFMA
#pragma unroll
        for (int m = 0; m < 4; m++) {
            int R = wr * 64 + m * 16 + lm;
            af[m] = *(const bf16x8*)(cA + R * 32 + (((quad + (R >> 1)) & 3) << 3));
        }
#pragma unroll
        for (int n = 0; n < 3; n++) {
            int R = wc * 96 + n * 16 + lm;
            bg[n] = *(const bf16x8*)(cB + R * 32 + (((quad + (R >> 1)) & 3) << 3));
        }
        __builtin_amdgcn_s_setprio(1);
#pragma unroll
        for (int m = 0; m < 4; m++)
#pragma unroll
            for (int n = 0; n < 3; n++)
                acc[m][n] = __builtin_amdgcn_mfma_f32_16x16x32_bf16(af[m], bg[n], acc[m][n], 0, 0, 0);
        __builtin_amdgcn_s_setprio(0);
        // phase 1: B n3-5, 12 MFMA
#pragma unroll
        for (int n = 3; n < 6; n++) {
            int R = wc * 96 + n * 16 + lm;
            bg[n] = *(const bf16x8*)(cB + R * 32 + (((quad + (R >> 1)) & 3) << 3));
        }
        __builtin_amdgcn_s_setprio(1);
#pragma unroll
        for (int m = 0; m < 4; m++)
#pragma unroll
            for (int n = 3; n < 6; n++)
                acc[m][n] = __builtin_amdgcn_mfma_f32_16x16x32_bf16(af[m], bg[n], acc[m][n], 0, 0, 0);
        __builtin_amdgcn_s_setprio(0);
        // boundary: tile tn-1 (oldest 5 loads) must be resident; keep the
        // newest 5 (tile tn) in flight.  Only the final 2 iters drain.
        if (pf) asm volatile("s_waitcnt vmcnt(5)" ::: "memory");
        else    asm volatile("s_waitcnt vmcnt(0)" ::: "memory");
        __builtin_amdgcn_s_barrier();
    };

    short* c0 = lds;
    short* c1 = lds + 10240;
    short* c2 = lds + 20480;
    stage(0, c0);
    stage(1, c1);
    asm volatile("s_waitcnt vmcnt(5)" ::: "memory");   // tile 0 resident
    __builtin_amdgcn_s_barrier();

    for (int t = 0; t < 64; t++) {
        tile(c0, c2, t + 2, t + 2 < 64);
        short* tmp = c0; c0 = c1; c1 = c2; c2 = tmp;
    }

    // epilogue: row-major bf16
#pragma unroll
    for (int m = 0; m < 4; m++)
#pragma unroll
        for (int n = 0; n < 6; n++)
#pragma unroll
            for (int r = 0; r < 4; r++) {
                int row = by * 128 + wr * 64 + m * 16 + quad * 4 + r;
                int col = bx * 192 + wc * 96 + n * 16 + lm;
                C[(long long)row * 6144 + col] = f2bf(acc[m][n][r]);
            }
}

// --------------------------------------------------- fused RoPE + V-trans
// 2048 blocks: bid<1024 -> rope (q,k cols of qkv, Q pre-scaled by
// SC*log2e); bid>=1024 -> vtrans (v cols -> v_t[o][t], LDS 64x64 tiles).
// Disjoint reads/writes, no ordering needed.
__global__ __launch_bounds__(256) void ropetrans_kernel(
    const short* __restrict__ qkv,
    short* __restrict__ qr, short* __restrict__ kr,
    short* __restrict__ v_t)
{
    __shared__ short lt[4096];
    int bid = blockIdx.x;
    int tid = threadIdx.x;
    if (bid < 1024) {
        const float QSC = 0.1275174150637756f;     // (1/sqrt(128))*log2(e)
        int idx = bid * 256 + tid;
        int d8 = (idx & 7) * 8;
        int h  = (idx >> 3) & 15;
        int s  = idx >> 7;
        long long io = (long long)s * 6144 + h * 128 + d8;
        long long oo = (long long)h * 262144 + (long long)s * 128 + d8;
        bf16x8 x1q = *(const bf16x8*)(qkv + io);
        bf16x8 x2q = *(const bf16x8*)(qkv + io + 64);
        bf16x8 x1k = *(const bf16x8*)(qkv + io + 2048);
        bf16x8 x2k = *(const bf16x8*)(qkv + io + 2112);
        bf16x8 o1q, o2q, o1k, o2k;
#pragma unroll
        for (int j = 0; j < 8; j++) {
            float inv = exp2f((float)(d8 + j) * -0.20762050593261719f);
            float ang = (float)s * inv;
            float sn, c;
            sincosf(ang, &sn, &c);
            float a1 = bf2f(x1q[j]), a2 = bf2f(x2q[j]);
            o1q[j] = f2bf((a1 * c - a2 * sn) * QSC);
            o2q[j] = f2bf((a1 * sn + a2 * c) * QSC);
            float b1 = bf2f(x1k[j]), b2 = bf2f(x2k[j]);
            o1k[j] = f2bf(b1 * c - b2 * sn);
            o2k[j] = f2bf(b1 * sn + b2 * c);
        }
        *(bf16x8*)(qr + oo)      = o1q;
        *(bf16x8*)(qr + oo + 64) = o2q;
        *(bf16x8*)(kr + oo)      = o1k;
        *(bf16x8*)(kr + oo + 64) = o2k;
    } else {
        int bt = (bid - 1024) & 31, bo = (bid - 1024) >> 5;
        int r = tid >> 3, c = tid & 7;
#pragma unroll
        for (int h = 0; h < 2; h++) {
            int row = h * 32 + r;                  // t-local
            bf16x8 v = *(const bf16x8*)(qkv + (long long)(bt * 64 + row) * 6144 + 4096 + bo * 64 + c * 8);
            *(bf16x8*)(lt + row * 64 + ((c ^ (row & 7)) << 3)) = v;
        }
        __syncthreads();
#pragma unroll
        for (int h = 0; h < 2; h++) {
            int o = h * 32 + r;                    // o-local
            bf16x8 ov;
#pragma unroll
            for (int k = 0; k < 8; k++) {
                int row = c * 8 + k;
                ov[k] = lt[row * 64 + ((((o >> 3) ^ (row & 7))) << 3) + (o & 7)];
            }
            *(bf16x8*)(v_t + (long long)(bo * 64 + o) * 2048 + bt * 64 + c * 8) = ov;
        }
    }
}

// ---------------------------------------------------------------- WO GEMM
// d_out[2048][2048] fp32 = attn bf16 @ wo_q^T.  128x64 tiles, BK=32,
// grid(32,16) = 512 = 2/CU.  4 waves (2Mx2N), per-wave 64x32 = 4m x 2n.
// Triple-buffered LDS (36 KB), 2-deep prefetch, counted vmcnt(3).
__global__ __launch_bounds__(256, 2) void gemm_wo(
    const short* __restrict__ A, const short* __restrict__ B,
    float* __restrict__ C)
{
    __shared__ short lds[18432];                   // 36 KiB = 3 x (8K A + 4K B)

    int wg = blockIdx.y * 32 + blockIdx.x;         // 512 wgs
    int sw = (wg & 7) * 64 + (wg >> 3);            // XCD-contiguous
    int bx = sw & 31, by = sw >> 5;

    const short* Ab = A + (long long)by * 128 * 2048;
    const short* Bb = B + (long long)bx * 64 * 2048;

    int tid = threadIdx.x, lane = tid & 63, wid = tid >> 6;
    int wr = wid >> 1, wc = wid & 1;               // wave grid 2x2
    int quad = lane >> 4, lm = lane & 15;

    f32x4 acc[4][2];
#pragma unroll
    for (int i = 0; i < 4; i++)
#pragma unroll
        for (int j = 0; j < 2; j++)
#pragma unroll
            for (int r = 0; r < 4; r++) acc[i][j][r] = 0.0f;

    auto stage = [&](int tn, short* buf) {
        short* dA = buf;                           // 4096 shorts (512 chunks)
        short* dB = buf + 4096;                    // 2048 shorts (256 chunks)
#pragma unroll
        for (int l = 0; l < 2; l++) {
            int ci  = l * 256 + tid;
            int row = ci >> 2;
            int kc  = ((ci & 3) - (row >> 1)) & 3;
            const short* gp = Ab + (long long)row * 2048 + tn * 32 + kc * 8;
            __builtin_amdgcn_global_load_lds((gmem_void*)gp, (lds_void*)(dA + ci * 8), 16, 0, 0);
        }
        {
            int ci  = tid;
            int row = ci >> 2;
            int kc  = ((ci & 3) - (row >> 1)) & 3;
            const short* gp = Bb + (long long)row * 2048 + tn * 32 + kc * 8;
            __builtin_amdgcn_global_load_lds((gmem_void*)gp, (lds_void*)(dB + ci * 8), 16, 0, 0);
        }
    };

    auto tile = [&](short* cur, short* nxt, int tn, bool pf) {
        if (pf) stage(tn, nxt);
        short* cA = cur;
        short* cB = cur + 4096;
        bf16x8 af[4], bg[2];
#pragma unroll
        for (int m = 0; m < 4; m++) {
            int R = wr * 64 + m * 16 + lm;
            af[m] = *(const bf16x8*)(cA + R * 32 + (((quad + (R >> 1)) & 3) << 3));
        }
#pragma unroll
        for (int n = 0; n < 2; n++) {
            int R = wc * 32 + n * 16 + lm;
            bg[n] = *(const bf16x8*)(cB + R * 32 + (((quad + (R >> 1)) & 3) << 3));
        }
        __builtin_amdgcn_s_setprio(1);
#pragma unroll
        for (int m = 0; m < 4; m++)
#pragma unroll
            for (int n = 0; n < 2; n++)
                acc[m][n] = __builtin_amdgcn_mfma_f32_16x16x32_bf16(af[m], bg[n], acc[m][n], 0, 0, 0);
        __builtin_amdgcn_s_setprio(0);
        if (pf) asm volatile("s_waitcnt vmcnt(3)" ::: "memory");
        else    asm volatile("s_waitcnt vmcnt(0)" ::: "memory");
        __builtin_amdgcn_s_barrier();
    };

    short* c0 = lds;
    short* c1 = lds + 6144;
    short* c2 = lds + 12288;
    stage(0, c0);
    stage(1, c1);
    asm volatile("s_waitcnt vmcnt(3)" ::: "memory");
    __builtin_amdgcn_s_barrier();

    for (int t = 0; t < 64; t++) {
        tile(c0, c2, t + 2, t + 2 < 64);
        short* tmp = c0; c0 = c1; c1 = c2; c2 = tmp;
    }

    // epilogue: fp32 row-major
#pragma unroll
    for (int m = 0; m < 4; m++)
#pragma unroll
        for (int n = 0; n < 2; n++)
#pragma unroll
            for (int r = 0; r < 4; r++) {
                int row = by * 128 + wr * 64 + m * 16 + quad * 4 + r;
                int col = bx * 64 + wc * 32 + n * 16 + lm;
                C[(long long)row * 2048 + col] = acc[m][n][r];
            }
}

// ---------------------------------------------------------------- flash attn
// 512 blocks: pair p = bid>>5 (0..15), h = (bid>>1)&15, z = bid&1 j-half.
// Legs qt=31-p then qt=p (16-17 jt/block, every CU = 33 jt).  Scores in
// log2 units (Q pre-scaled).  Per-lane partial l-sum (reduced per leg);
// vote-gated max reduce (slow path only when a lane exceeds m+11.5);
// setprio around MFMA clusters.  m/l partials in log2 units.  [r17]
__global__ __launch_bounds__(256) void flash_kernel(
    const short* __restrict__ q_r, const short* __restrict__ k_r,
    const short* __restrict__ v_t, float* __restrict__ Opart,
    float* __restrict__ mpart, float* __restrict__ lpart)
{
    const float THR = 11.5f;                       // ~8 nats in log2 units
    int bid = blockIdx.x;
    int p = bid >> 5;
    int h = (bid >> 1) & 15;
    int z = bid & 1;

    int tid = threadIdx.x, lane = tid & 63, wv = tid >> 6;
    int quad = lane >> 4, lm = lane & 15;

    __shared__ short lK[64 * 128];
    __shared__ short lV[128 * 64];
    __shared__ short lP[64 * 64];

    const short* kb = k_r + h * 262144;
    const short* vb = v_t + h * 128 * 2048;

    for (int leg = 0; leg < 2; leg++) {
        int qt = leg ? p : 31 - p;
        int n  = qt + 1;
        int jhalf = (n + 1) >> 1;
        int jb = z ? jhalf : 0;
        int je = z ? n : jhalf;

        const short* qb = q_r + h * 262144 + (qt * 64 + wv * 16) * 128;
        bf16x8 aq[4];
#pragma unroll
        for (int kc = 0; kc < 4; kc++)
            aq[kc] = *(const bf16x8*)(qb + lm * 128 + kc * 32 + quad * 8);

        f32x4 ao[8];
#pragma unroll
        for (int nt = 0; nt < 8; nt++)
#pragma unroll
            for (int r = 0; r < 4; r++) ao[nt][r] = 0.0f;
        float mrow[4], lrow[4];                    // lrow = PER-LANE partial
#pragma unroll
        for (int r = 0; r < 4; r++) { mrow[r] = -1e30f; lrow[r] = 0.0f; }

        if (jb < je) {
#pragma unroll
            for (int i = 0; i < 4; i++) {
                int ci = i * 256 + tid;
                int r = ci >> 4, cp = ci & 15;
                int c = (cp & 8) | ((cp & 7) ^ (r & 7));
                const short* gp = kb + (jb * 64 + r) * 128 + c * 8;
                __builtin_amdgcn_global_load_lds((gmem_void*)gp, (lds_void*)(lK + ci * 8), 16, 0, 0);
            }
        }
        __syncthreads();

        for (int jt = jb; jt < je; jt++) {
#pragma unroll
            for (int i = 0; i < 4; i++) {
                int ci = i * 256 + tid;
                int r = ci >> 3, cp = ci & 7;
                int c = cp ^ (r & 7);
                const short* gp = vb + r * 2048 + jt * 64 + c * 8;
                __builtin_amdgcn_global_load_lds((gmem_void*)gp, (lds_void*)(lV + ci * 8), 16, 0, 0);
            }
            f32x4 as[4];
#pragma unroll
            for (int nt = 0; nt < 4; nt++)
#pragma unroll
                for (int r = 0; r < 4; r++) as[nt][r] = 0.0f;
            __builtin_amdgcn_s_setprio(1);
#pragma unroll
            for (int kc = 0; kc < 4; kc++) {
#pragma unroll
                for (int nt = 0; nt < 4; nt++) {
                    int r = nt * 16 + lm;
                    int c = kc * 4 + quad;
                    int slot = (c & 8) | ((c & 7) ^ (r & 7));
                    bf16x8 bk = *(const bf16x8*)(lK + (r * 16 + slot) * 8);
                    as[nt] = __builtin_amdgcn_mfma_f32_16x16x32_bf16(aq[kc], bk, as[nt], 0, 0, 0);
                }
            }
            __builtin_amdgcn_s_setprio(0);
            if (jt == qt) {                        // diag mask only
#pragma unroll
                for (int nt = 0; nt < 4; nt++)
#pragma unroll
                    for (int r = 0; r < 4; r++) {
                        int qg = wv * 16 + quad * 4 + r;
                        int tg = nt * 16 + lm;
                        if (tg > qg) as[nt][r] = -1e30f;
                    }
            }
#pragma unroll
            for (int r = 0; r < 4; r++) {
                float lmax = fmaxf(fmaxf(as[0][r], as[1][r]), fmaxf(as[2][r], as[3][r]));
                // vote-gated max: common case (lmax within THR of running
                // max) -> no reduce, no rescale, no shuffles.
                if (__any(lmax > mrow[r] + THR)) {
                    float mx = lmax;
#pragma unroll
                    for (int off = 1; off < 16; off <<= 1) mx = fmaxf(mx, __shfl_xor(mx, off));
                    if (mx > mrow[r] + THR) {
                        float alpha = exp2f(mrow[r] - mx);   // group-uniform
                        lrow[r] *= alpha;
#pragma unroll
                        for (int nt = 0; nt < 8; nt++) ao[nt][r] *= alpha;
                        mrow[r] = mx;
                    }
                }
                float ps = 0.0f;
#pragma unroll
                for (int nt = 0; nt < 4; nt++) {
                    float pv = exp2f(as[nt][r] - mrow[r]);
                    as[nt][r] = pv;
                    ps += pv;
                }
                lrow[r] += ps;                     // per-lane partial
                int row = wv * 16 + quad * 4 + r;
#pragma unroll
                for (int nt = 0; nt < 4; nt++) {
                    int slot = (nt * 2 + (lm >> 3) + 2 * quad) & 7;   // uniform
                    lP[row * 64 + slot * 8 + (lm & 7)] = f2bf(as[nt][r]);
                }
            }
            __syncthreads();
            if (jt + 1 < je) {
#pragma unroll
                for (int i = 0; i < 4; i++) {
                    int ci = i * 256 + tid;
                    int r = ci >> 4, cp = ci & 15;
                    int c = (cp & 8) | ((cp & 7) ^ (r & 7));
                    const short* gp = kb + ((jt + 1) * 64 + r) * 128 + c * 8;
                    __builtin_amdgcn_global_load_lds((gmem_void*)gp, (lds_void*)(lK + ci * 8), 16, 0, 0);
                }
            }
            __builtin_amdgcn_s_setprio(1);
#pragma unroll
            for (int kt = 0; kt < 2; kt++) {
                int prow = wv * 16 + lm;
                int slot = (kt * 4 + quad + 2 * (lm >> 2)) & 7;       // matches write
                bf16x8 ap = *(const bf16x8*)(lP + prow * 64 + slot * 8);
#pragma unroll
                for (int nt = 0; nt < 8; nt++) {
                    int r = nt * 16 + lm;
                    int c = kt * 4 + quad;
                    int vslot = c ^ (r & 7);
                    bf16x8 bv = *(const bf16x8*)(lV + (r * 8 + vslot) * 8);
                    ao[nt] = __builtin_amdgcn_mfma_f32_16x16x32_bf16(ap, bv, ao[nt], 0, 0, 0);
                }
            }
            __builtin_amdgcn_s_setprio(0);
            __syncthreads();
        }

        // leg epilogue: reduce the per-lane l partials (16-wide), store.
        float* Ob = Opart + (long long)z * 4194304;
#pragma unroll
        for (int r = 0; r < 4; r++) {
            float l = lrow[r];
#pragma unroll
            for (int off = 1; off < 16; off <<= 1) l += __shfl_xor(l, off);
            int sg = qt * 64 + wv * 16 + quad * 4 + r;
#pragma unroll
            for (int nt = 0; nt < 8; nt++) {
                int dg = h * 128 + nt * 16 + lm;
                Ob[(long long)sg * 2048 + dg] = ao[nt][r];
            }
            if (lm == 0) {
                mpart[z * 32768 + h * 2048 + sg] = mrow[r];   // log2 units
                lpart[z * 32768 + h * 2048 + sg] = l;
            }
        }
    }
}

// ---------------------------------------------------------------- combine
// m partials are in log2 units -> exp2f.
__global__ __launch_bounds__(256) void combine_kernel(
    const float* __restrict__ O0, const float* __restrict__ O1,
    const float* __restrict__ mpart, const float* __restrict__ lpart,
    short* __restrict__ attn)
{
    int idx = blockIdx.x * 256 + threadIdx.x;   // 1M threads
    int e = idx * 4;
    int s = e >> 11, h = (e & 2047) >> 7;
    float m0 = mpart[h * 2048 + s], m1 = mpart[32768 + h * 2048 + s];
    float l0 = lpart[h * 2048 + s], l1 = lpart[32768 + h * 2048 + s];
    float M = fmaxf(m0, m1);
    float w0 = exp2f(m0 - M), w1 = exp2f(m1 - M);
    float inv = 1.0f / (l0 * w0 + l1 * w1);
    float4 a = *(const float4*)(O0 + e);
    float4 b = *(const float4*)(O1 + e);
    short4 o;
    o.x = f2bf((a.x * w0 + b.x * w1) * inv);
    o.y = f2bf((a.y * w0 + b.y * w1) * inv);
    o.z = f2bf((a.z * w0 + b.z * w1) * inv);
    o.w = f2bf((a.w * w0 + b.w * w1) * inv);
    *(short4*)(attn + e) = o;
}

// ---------------------------------------------------------------- launch
extern "C" void kernel_launch(void* const* d_in, const int* in_sizes, int n_in,
                              void* d_out, int out_size, void* d_ws, size_t ws_size,
                              hipStream_t stream)
{
    const void* x  = d_in[0];
    const void* wq = d_in[2];
    const void* wk = d_in[3];
    const void* wv = d_in[4];
    const void* wo = d_in[5];

    char* ws = (char*)d_ws;
    size_t off = 0;
    auto alloc = [&](size_t b) { void* p = ws + off; off += (b + 255) & ~(size_t)255; return p; };
    short* wqkv_q = (short*)alloc(25165824);   // [6144][2048] bf16 (q,k,v)
    short* wo_q   = (short*)alloc(8388608);
    float* Opart  = (float*)alloc(33554432);   // [2][2048][2048] fp32
    short* qkv    = (short*)Opart;             // alias: [2048][6144] bf16, dies pre-flash
    short* v_t    = (short*)alloc(8388608);    // [o][t]
    short* q_r    = (short*)alloc(8388608);    // [h][s][128]
    short* k_r    = (short*)alloc(8388608);
    short* attn   = (short*)alloc(8388608);    // [s][2048]
    short* x_bf   = (short*)alloc(8388608);
    float* mpart  = (float*)alloc(262144);     // [2][16][2048]
    float* lpart  = (float*)alloc(262144);
    int*   flag   = (int*)alloc(256);
    if (off > ws_size) return;                 // ~110 MB

    zero_flag<<<1, 64, 0, stream>>>(flag);
    detect_kernel<<<256, 256, 0, stream>>>(
        (const unsigned short*)x, in_sizes[0], flag);
    convert_kernel<<<4096, 256, 0, stream>>>(x, x_bf, 4194304, flag);

    quant_kernel<<<16384, 256, 0, stream>>>(wq, wk, wv, wo,
        wqkv_q, wqkv_q + 4194304, wqkv_q + 8388608, wo_q, flag);

    gemm_qkv<<<dim3(32, 16), 256, 0, stream>>>(x_bf, wqkv_q, qkv);

    ropetrans_kernel<<<2048, 256, 0, stream>>>(qkv, q_r, k_r, v_t);

    flash_kernel<<<512, 256, 0, stream>>>(q_r, k_r, v_t, Opart, mpart, lpart);
    combine_kernel<<<4096, 256, 0, stream>>>(
        Opart, Opart + 4194304, mpart, lpart, attn);

    gemm_wo<<<dim3(32, 16), 256, 0, stream>>>(attn, wo_q, (float*)d_out);
}

// Round 11
// 293.740 us; speedup vs baseline: 1.0529x; 1.0108x over previous
//
#include <hip/hip_runtime.h>
#include <cstdint>
#include <cstddef>

// BitLlamaAttention: B=1, S=2048, HIDDEN=2048, NH=16, HD=128, GROUP=128
// r20: r19 base (296.9us: qkv B-locality FETCH 137->45MB, rope+vtrans fused).
//  1) flash counted-vmcnt pipeline: lK double-buffered (56KB LDS); V[jt]+
//     K[jt+1] issued together at loop top; barrier#1 = vmcnt(4) (V resident,
//     K-next IN FLIGHT across it); barrier#2 = vmcnt(0) with full-iteration
//     window behind it.  Removes the 2x full-drain __syncthreads per jt
//     (the guide's ~20% barrier-drain stall), K latency window = whole iter.
//  2) gemm_wo XCD swizzle flipped to B-locality (1MB B-slice/XCD, mirror of
//     r19's qkv win).
//  3) convert+quant fused into prep_kernel (one less launch).

typedef __attribute__((ext_vector_type(8))) short bf16x8;
typedef __attribute__((ext_vector_type(4))) float f32x4;
typedef __attribute__((address_space(3))) void lds_void;
typedef const __attribute__((address_space(1))) void gmem_void;

__device__ __forceinline__ short f2bf(float x) {
    union { float f; uint32_t u; } c; c.f = x;
    uint32_t r = (c.u + 0x7FFFu + ((c.u >> 16) & 1u)) >> 16;
    return (short)r;
}
__device__ __forceinline__ float bf2f(short x) {
    union { uint32_t u; float f; } c; c.u = ((uint32_t)(uint16_t)x) << 16;
    return c.f;
}

// ------------------------------------------------------------ dtype probe
__global__ __launch_bounds__(64) void zero_flag(int* f) {
    if (threadIdx.x == 0) *f = 0;
}

__global__ __launch_bounds__(256) void detect_kernel(
    const unsigned short* __restrict__ p, int n, int* __restrict__ flag)
{
    int tid = blockIdx.x * 256 + threadIdx.x;
    int cnt = 0;
    for (int i = tid; i < n; i += 65536) {
        int e = (p[i] >> 7) & 0xFF;
        cnt += (e >= 0xF0) ? 1 : 0;
    }
#pragma unroll
    for (int off = 1; off < 64; off <<= 1) cnt += __shfl_xor(cnt, off);
    if ((threadIdx.x & 63) == 0 && cnt) atomicAdd(flag, cnt);
}

// ------------------------------------------------- fused convert + quant
// bid<4096: canonicalize hidden_states to bf16 (4 elems/thread).
// bid>=4096: ternary groupwise quant of 4 matrices (4 elems/thread,
// group=128 elems=32 lanes, 5-round reduce).
__global__ __launch_bounds__(256) void prep_kernel(
    const void* __restrict__ x, short* __restrict__ x_bf,
    const void* __restrict__ w0, const void* __restrict__ w1,
    const void* __restrict__ w2, const void* __restrict__ w3,
    short* __restrict__ q0, short* __restrict__ q1,
    short* __restrict__ q2, short* __restrict__ q3,
    const int* __restrict__ flag)
{
    bool isf32 = (*flag > 1000);
    int bid = blockIdx.x, tid = threadIdx.x;
    if (bid < 4096) {
        int i = (bid * 256 + tid) * 4;
        if (isf32) {
            float4 v = *(const float4*)((const float*)x + i);
            short4 o;
            o.x = f2bf(v.x); o.y = f2bf(v.y); o.z = f2bf(v.z); o.w = f2bf(v.w);
            *(short4*)(x_bf + i) = o;
        } else {
            *(short4*)(x_bf + i) = *(const short4*)((const short*)x + i);
        }
        return;
    }
    int t   = (bid - 4096) * 256 + tid;            // 4M threads
    int mat = t >> 20;
    int e4  = t & 1048575;
    const void* w = (mat == 0) ? w0 : (mat == 1) ? w1 : (mat == 2) ? w2 : w3;
    short*      q = (mat == 0) ? q0 : (mat == 1) ? q1 : (mat == 2) ? q2 : q3;
    float a0, a1, a2, a3;
    if (isf32) {
        float4 v = *(const float4*)((const float*)w + (long long)e4 * 4);
        a0 = v.x; a1 = v.y; a2 = v.z; a3 = v.w;
    } else {
        short4 v = *(const short4*)((const short*)w + (long long)e4 * 4);
        a0 = bf2f(v.x); a1 = bf2f(v.y); a2 = bf2f(v.z); a3 = bf2f(v.w);
    }
    float s = fabsf(a0) + fabsf(a1) + fabsf(a2) + fabsf(a3);
#pragma unroll
    for (int off = 1; off < 32; off <<= 1) s += __shfl_xor(s, off);
    float scale = fmaxf(s * (1.0f / 128.0f), 1e-8f);
    float inv = 1.0f / scale;
    auto qz = [&](float a) -> short {
        float na = a * inv;
        return f2bf((na > 0.5f) ? scale : (na < -0.5f) ? -scale : 0.0f);
    };
    short4 o;
    o.x = qz(a0); o.y = qz(a1); o.z = qz(a2); o.w = qz(a3);
    *(short4*)(q + (long long)e4 * 4) = o;
}

// ---------------------------------------------------------------- QKV GEMM
// C[2048][6144] = x_bf[2048x2048] @ wqkv^T[6144x2048].  128x192 tiles,
// BK=32, grid(32,16) = 512 blocks = 2/CU.  Triple-buffered LDS, 2-deep
// prefetch, counted vmcnt(5).  XCD swizzle: B-locality (3MB B-slice in L2).
__global__ __launch_bounds__(256, 2) void gemm_qkv(
    const short* __restrict__ A, const short* __restrict__ B,
    short* __restrict__ C)
{
    __shared__ short lds[30720];                   // 60 KiB = 3 x (8K A + 12K B)

    int wg = blockIdx.y * 32 + blockIdx.x;         // 512 wgs, 512%8==0
    int sw = (wg & 7) * 64 + (wg >> 3);            // XCD-contiguous chunks
    int bx = sw >> 4, by = sw & 15;                // B-locality: 4 bx/XCD

    const short* Ab = A + (long long)by * 128 * 2048;
    const short* Bb = B + (long long)bx * 192 * 2048;

    int tid = threadIdx.x, lane = tid & 63, wid = tid >> 6;
    int wr = wid >> 1, wc = wid & 1;               // wave grid 2x2
    int quad = lane >> 4, lm = lane & 15;

    f32x4 acc[4][6];
#pragma unroll
    for (int i = 0; i < 4; i++)
#pragma unroll
        for (int j = 0; j < 6; j++)
#pragma unroll
            for (int r = 0; r < 4; r++) acc[i][j][r] = 0.0f;

    auto stage = [&](int tn, short* buf) {
        short* dA = buf;                           // 4096 shorts
        short* dB = buf + 4096;                    // 6144 shorts
#pragma unroll
        for (int l = 0; l < 2; l++) {
            int ci  = l * 256 + tid;               // 512 chunks of 16B
            int row = ci >> 2;
            int kc  = ((ci & 3) - (row >> 1)) & 3; // inverse swizzle on src
            const short* gp = Ab + (long long)row * 2048 + tn * 32 + kc * 8;
            __builtin_amdgcn_global_load_lds((gmem_void*)gp, (lds_void*)(dA + ci * 8), 16, 0, 0);
        }
#pragma unroll
        for (int l = 0; l < 3; l++) {
            int ci  = l * 256 + tid;               // 768 chunks of 16B
            int row = ci >> 2;
            int kc  = ((ci & 3) - (row >> 1)) & 3;
            const short* gp = Bb + (long long)row * 2048 + tn * 32 + kc * 8;
            __builtin_amdgcn_global_load_lds((gmem_void*)gp, (lds_void*)(dB + ci * 8), 16, 0, 0);
        }
    };

    auto tile = [&](short* cur, short* nxt, int tn, bool pf) {
        if (pf) stage(tn, nxt);                    // issue-early prefetch
        short* cA = cur;
        short* cB = cur + 4096;
        bf16x8 af[4], bg[6];
#pragma unroll
        for (int m = 0; m < 4; m++) {
            int R = wr * 64 + m * 16 + lm;
            af[m] = *(const bf16x8*)(cA + R * 32 + (((quad + (R >> 1)) & 3) << 3));
        }
#pragma unroll
        for (int n = 0; n < 3; n++) {
            int R = wc * 96 + n * 16 + lm;
            bg[n] = *(const bf16x8*)(cB + R * 32 + (((quad + (R >> 1)) & 3) << 3));
        }
        __builtin_amdgcn_s_setprio(1);
#pragma unroll
        for (int m = 0; m < 4; m++)
#pragma unroll
            for (int n = 0; n < 3; n++)
                acc[m][n] = __builtin_amdgcn_mfma_f32_16x16x32_bf16(af[m], bg[n], acc[m][n], 0, 0, 0);
        __builtin_amdgcn_s_setprio(0);
#pragma unroll
        for (int n = 3; n < 6; n++) {
            int R = wc * 96 + n * 16 + lm;
            bg[n] = *(const bf16x8*)(cB + R * 32 + (((quad + (R >> 1)) & 3) << 3));
        }
        __builtin_amdgcn_s_setprio(1);
#pragma unroll
        for (int m = 0; m < 4; m++)
#pragma unroll
            for (int n = 3; n < 6; n++)
                acc[m][n] = __builtin_amdgcn_mfma_f32_16x16x32_bf16(af[m], bg[n], acc[m][n], 0, 0, 0);
        __builtin_amdgcn_s_setprio(0);
        if (pf) asm volatile("s_waitcnt vmcnt(5)" ::: "memory");
        else    asm volatile("s_waitcnt vmcnt(0)" ::: "memory");
        __builtin_amdgcn_s_barrier();
    };

    short* c0 = lds;
    short* c1 = lds + 10240;
    short* c2 = lds + 20480;
    stage(0, c0);
    stage(1, c1);
    asm volatile("s_waitcnt vmcnt(5)" ::: "memory");   // tile 0 resident
    __builtin_amdgcn_s_barrier();

    for (int t = 0; t < 64; t++) {
        tile(c0, c2, t + 2, t + 2 < 64);
        short* tmp = c0; c0 = c1; c1 = c2; c2 = tmp;
    }

    // epilogue: row-major bf16
#pragma unroll
    for (int m = 0; m < 4; m++)
#pragma unroll
        for (int n = 0; n < 6; n++)
#pragma unroll
            for (int r = 0; r < 4; r++) {
                int row = by * 128 + wr * 64 + m * 16 + quad * 4 + r;
                int col = bx * 192 + wc * 96 + n * 16 + lm;
                C[(long long)row * 6144 + col] = f2bf(acc[m][n][r]);
            }
}

// --------------------------------------------------- fused RoPE + V-trans
__global__ __launch_bounds__(256) void ropetrans_kernel(
    const short* __restrict__ qkv,
    short* __restrict__ qr, short* __restrict__ kr,
    short* __restrict__ v_t)
{
    __shared__ short lt[4096];
    int bid = blockIdx.x;
    int tid = threadIdx.x;
    if (bid < 1024) {
        const float QSC = 0.1275174150637756f;     // (1/sqrt(128))*log2(e)
        int idx = bid * 256 + tid;
        int d8 = (idx & 7) * 8;
        int h  = (idx >> 3) & 15;
        int s  = idx >> 7;
        long long io = (long long)s * 6144 + h * 128 + d8;
        long long oo = (long long)h * 262144 + (long long)s * 128 + d8;
        bf16x8 x1q = *(const bf16x8*)(qkv + io);
        bf16x8 x2q = *(const bf16x8*)(qkv + io + 64);
        bf16x8 x1k = *(const bf16x8*)(qkv + io + 2048);
        bf16x8 x2k = *(const bf16x8*)(qkv + io + 2112);
        bf16x8 o1q, o2q, o1k, o2k;
#pragma unroll
        for (int j = 0; j < 8; j++) {
            float inv = exp2f((float)(d8 + j) * -0.20762050593261719f);
            float ang = (float)s * inv;
            float sn, c;
            sincosf(ang, &sn, &c);
            float a1 = bf2f(x1q[j]), a2 = bf2f(x2q[j]);
            o1q[j] = f2bf((a1 * c - a2 * sn) * QSC);
            o2q[j] = f2bf((a1 * sn + a2 * c) * QSC);
            float b1 = bf2f(x1k[j]), b2 = bf2f(x2k[j]);
            o1k[j] = f2bf(b1 * c - b2 * sn);
            o2k[j] = f2bf(b1 * sn + b2 * c);
        }
        *(bf16x8*)(qr + oo)      = o1q;
        *(bf16x8*)(qr + oo + 64) = o2q;
        *(bf16x8*)(kr + oo)      = o1k;
        *(bf16x8*)(kr + oo + 64) = o2k;
    } else {
        int bt = (bid - 1024) & 31, bo = (bid - 1024) >> 5;
        int r = tid >> 3, c = tid & 7;
#pragma unroll
        for (int h = 0; h < 2; h++) {
            int row = h * 32 + r;                  // t-local
            bf16x8 v = *(const bf16x8*)(qkv + (long long)(bt * 64 + row) * 6144 + 4096 + bo * 64 + c * 8);
            *(bf16x8*)(lt + row * 64 + ((c ^ (row & 7)) << 3)) = v;
        }
        __syncthreads();
#pragma unroll
        for (int h = 0; h < 2; h++) {
            int o = h * 32 + r;                    // o-local
            bf16x8 ov;
#pragma unroll
            for (int k = 0; k < 8; k++) {
                int row = c * 8 + k;
                ov[k] = lt[row * 64 + ((((o >> 3) ^ (row & 7))) << 3) + (o & 7)];
            }
            *(bf16x8*)(v_t + (long long)(bo * 64 + o) * 2048 + bt * 64 + c * 8) = ov;
        }
    }
}

// ---------------------------------------------------------------- WO GEMM
// d_out[2048][2048] fp32 = attn bf16 @ wo_q^T.  128x64 tiles, BK=32,
// grid(32,16) = 512 = 2/CU.  Triple-buffered LDS, counted vmcnt(3).
// XCD swizzle: B-locality (1MB B-slice/XCD in L2).
__global__ __launch_bounds__(256, 2) void gemm_wo(
    const short* __restrict__ A, const short* __restrict__ B,
    float* __restrict__ C)
{
    __shared__ short lds[18432];                   // 36 KiB = 3 x (8K A + 4K B)

    int wg = blockIdx.y * 32 + blockIdx.x;         // 512 wgs
    int sw = (wg & 7) * 64 + (wg >> 3);            // XCD-contiguous
    int bx = sw >> 4, by = sw & 15;                // B-locality: 4 bx/XCD

    const short* Ab = A + (long long)by * 128 * 2048;
    const short* Bb = B + (long long)bx * 64 * 2048;

    int tid = threadIdx.x, lane = tid & 63, wid = tid >> 6;
    int wr = wid >> 1, wc = wid & 1;               // wave grid 2x2
    int quad = lane >> 4, lm = lane & 15;

    f32x4 acc[4][2];
#pragma unroll
    for (int i = 0; i < 4; i++)
#pragma unroll
        for (int j = 0; j < 2; j++)
#pragma unroll
            for (int r = 0; r < 4; r++) acc[i][j][r] = 0.0f;

    auto stage = [&](int tn, short* buf) {
        short* dA = buf;                           // 4096 shorts (512 chunks)
        short* dB = buf + 4096;                    // 2048 shorts (256 chunks)
#pragma unroll
        for (int l = 0; l < 2; l++) {
            int ci  = l * 256 + tid;
            int row = ci >> 2;
            int kc  = ((ci & 3) - (row >> 1)) & 3;
            const short* gp = Ab + (long long)row * 2048 + tn * 32 + kc * 8;
            __builtin_amdgcn_global_load_lds((gmem_void*)gp, (lds_void*)(dA + ci * 8), 16, 0, 0);
        }
        {
            int ci  = tid;
            int row = ci >> 2;
            int kc  = ((ci & 3) - (row >> 1)) & 3;
            const short* gp = Bb + (long long)row * 2048 + tn * 32 + kc * 8;
            __builtin_amdgcn_global_load_lds((gmem_void*)gp, (lds_void*)(dB + ci * 8), 16, 0, 0);
        }
    };

    auto tile = [&](short* cur, short* nxt, int tn, bool pf) {
        if (pf) stage(tn, nxt);
        short* cA = cur;
        short* cB = cur + 4096;
        bf16x8 af[4], bg[2];
#pragma unroll
        for (int m = 0; m < 4; m++) {
            int R = wr * 64 + m * 16 + lm;
            af[m] = *(const bf16x8*)(cA + R * 32 + (((quad + (R >> 1)) & 3) << 3));
        }
#pragma unroll
        for (int n = 0; n < 2; n++) {
            int R = wc * 32 + n * 16 + lm;
            bg[n] = *(const bf16x8*)(cB + R * 32 + (((quad + (R >> 1)) & 3) << 3));
        }
        __builtin_amdgcn_s_setprio(1);
#pragma unroll
        for (int m = 0; m < 4; m++)
#pragma unroll
            for (int n = 0; n < 2; n++)
                acc[m][n] = __builtin_amdgcn_mfma_f32_16x16x32_bf16(af[m], bg[n], acc[m][n], 0, 0, 0);
        __builtin_amdgcn_s_setprio(0);
        if (pf) asm volatile("s_waitcnt vmcnt(3)" ::: "memory");
        else    asm volatile("s_waitcnt vmcnt(0)" ::: "memory");
        __builtin_amdgcn_s_barrier();
    };

    short* c0 = lds;
    short* c1 = lds + 6144;
    short* c2 = lds + 12288;
    stage(0, c0);
    stage(1, c1);
    asm volatile("s_waitcnt vmcnt(3)" ::: "memory");
    __builtin_amdgcn_s_barrier();

    for (int t = 0; t < 64; t++) {
        tile(c0, c2, t + 2, t + 2 < 64);
        short* tmp = c0; c0 = c1; c1 = c2; c2 = tmp;
    }

    // epilogue: fp32 row-major
#pragma unroll
    for (int m = 0; m < 4; m++)
#pragma unroll
        for (int n = 0; n < 2; n++)
#pragma unroll
            for (int r = 0; r < 4; r++) {
                int row = by * 128 + wr * 64 + m * 16 + quad * 4 + r;
                int col = bx * 64 + wc * 32 + n * 16 + lm;
                C[(long long)row * 2048 + col] = acc[m][n][r];
            }
}

// ---------------------------------------------------------------- flash attn
// 512 blocks: pair p = bid>>5, h = (bid>>1)&15, z = bid&1 j-half.  Legs
// qt=31-p then qt=p.  Counted-vmcnt pipeline: lK double-buffered; V[jt] +
// K[jt+1] issued at loop top; barrier#1 = vmcnt(4) lgkmcnt(0) (V + lP
// resident, K-next in flight ACROSS the barrier); barrier#2 = vmcnt(0)
// with the whole iteration behind it.  Scores in log2 units; per-lane
// partial l; vote-gated max (THR=11.5); setprio on MFMA clusters.
__global__ __launch_bounds__(256) void flash_kernel(
    const short* __restrict__ q_r, const short* __restrict__ k_r,
    const short* __restrict__ v_t, float* __restrict__ Opart,
    float* __restrict__ mpart, float* __restrict__ lpart)
{
    const float THR = 11.5f;                       // ~8 nats in log2 units
    int bid = blockIdx.x;
    int p = bid >> 5;
    int h = (bid >> 1) & 15;
    int z = bid & 1;

    int tid = threadIdx.x, lane = tid & 63, wv = tid >> 6;
    int quad = lane >> 4, lm = lane & 15;

    __shared__ short lK[2][64 * 128];              // double-buffered
    __shared__ short lV[128 * 64];
    __shared__ short lP[64 * 64];

    const short* kb = k_r + h * 262144;
    const short* vb = v_t + h * 128 * 2048;

    auto stageK = [&](int jtgt, short* dst) {
#pragma unroll
        for (int i = 0; i < 4; i++) {
            int ci = i * 256 + tid;
            int r = ci >> 4, cp = ci & 15;
            int c = (cp & 8) | ((cp & 7) ^ (r & 7));
            const short* gp = kb + (jtgt * 64 + r) * 128 + c * 8;
            __builtin_amdgcn_global_load_lds((gmem_void*)gp, (lds_void*)(dst + ci * 8), 16, 0, 0);
        }
    };
    auto stageV = [&](int jtgt) {
#pragma unroll
        for (int i = 0; i < 4; i++) {
            int ci = i * 256 + tid;
            int r = ci >> 3, cp = ci & 7;
            int c = cp ^ (r & 7);
            const short* gp = vb + r * 2048 + jtgt * 64 + c * 8;
            __builtin_amdgcn_global_load_lds((gmem_void*)gp, (lds_void*)(lV + ci * 8), 16, 0, 0);
        }
    };

    for (int leg = 0; leg < 2; leg++) {
        int qt = leg ? p : 31 - p;
        int n  = qt + 1;
        int jhalf = (n + 1) >> 1;
        int jb = z ? jhalf : 0;
        int je = z ? n : jhalf;

        const short* qb = q_r + h * 262144 + (qt * 64 + wv * 16) * 128;
        bf16x8 aq[4];
#pragma unroll
        for (int kc = 0; kc < 4; kc++)
            aq[kc] = *(const bf16x8*)(qb + lm * 128 + kc * 32 + quad * 8);

        f32x4 ao[8];
#pragma unroll
        for (int nt = 0; nt < 8; nt++)
#pragma unroll
            for (int r = 0; r < 4; r++) ao[nt][r] = 0.0f;
        float mrow[4], lrow[4];                    // lrow = PER-LANE partial
#pragma unroll
        for (int r = 0; r < 4; r++) { mrow[r] = -1e30f; lrow[r] = 0.0f; }

        int cur = 0;
        if (jb < je) stageK(jb, lK[0]);
        asm volatile("s_waitcnt vmcnt(0)" ::: "memory");
        __builtin_amdgcn_s_barrier();

        for (int jt = jb; jt < je; jt++) {
            bool pk = (jt + 1 < je);
            stageV(jt);                            // 4 loads
            if (pk) stageK(jt + 1, lK[cur ^ 1]);   // 4 loads, cross-barrier
            f32x4 as[4];
#pragma unroll
            for (int nt = 0; nt < 4; nt++)
#pragma unroll
                for (int r = 0; r < 4; r++) as[nt][r] = 0.0f;
            __builtin_amdgcn_s_setprio(1);
#pragma unroll
            for (int kc = 0; kc < 4; kc++) {
#pragma unroll
                for (int nt = 0; nt < 4; nt++) {
                    int r = nt * 16 + lm;
                    int c = kc * 4 + quad;
                    int slot = (c & 8) | ((c & 7) ^ (r & 7));
                    bf16x8 bk = *(const bf16x8*)(lK[cur] + (r * 16 + slot) * 8);
                    as[nt] = __builtin_amdgcn_mfma_f32_16x16x32_bf16(aq[kc], bk, as[nt], 0, 0, 0);
                }
            }
            __builtin_amdgcn_s_setprio(0);
            if (jt == qt) {                        // diag mask only
#pragma unroll
                for (int nt = 0; nt < 4; nt++)
#pragma unroll
                    for (int r = 0; r < 4; r++) {
                        int qg = wv * 16 + quad * 4 + r;
                        int tg = nt * 16 + lm;
                        if (tg > qg) as[nt][r] = -1e30f;
                    }
            }
#pragma unroll
            for (int r = 0; r < 4; r++) {
                float lmax = fmaxf(fmaxf(as[0][r], as[1][r]), fmaxf(as[2][r], as[3][r]));
                if (__any(lmax > mrow[r] + THR)) {
                    float mx = lmax;
#pragma unroll
                    for (int off = 1; off < 16; off <<= 1) mx = fmaxf(mx, __shfl_xor(mx, off));
                    if (mx > mrow[r] + THR) {
                        float alpha = exp2f(mrow[r] - mx);   // group-uniform
                        lrow[r] *= alpha;
#pragma unroll
                        for (int nt = 0; nt < 8; nt++) ao[nt][r] *= alpha;
                        mrow[r] = mx;
                    }
                }
                float ps = 0.0f;
#pragma unroll
                for (int nt = 0; nt < 4; nt++) {
                    float pv = exp2f(as[nt][r] - mrow[r]);
                    as[nt][r] = pv;
                    ps += pv;
                }
                lrow[r] += ps;                     // per-lane partial
                int row = wv * 16 + quad * 4 + r;
#pragma unroll
                for (int nt = 0; nt < 4; nt++) {
                    int slot = (nt * 2 + (lm >> 3) + 2 * quad) & 7;   // uniform
                    lP[row * 64 + slot * 8 + (lm & 7)] = f2bf(as[nt][r]);
                }
            }
            // barrier #1: V (oldest 4 loads) + lP must be resident.
            // K-next (newest 4) stays IN FLIGHT across the barrier.
            if (pk) asm volatile("s_waitcnt vmcnt(4) lgkmcnt(0)" ::: "memory");
            else    asm volatile("s_waitcnt vmcnt(0) lgkmcnt(0)" ::: "memory");
            __builtin_amdgcn_s_barrier();
            __builtin_amdgcn_s_setprio(1);
#pragma unroll
            for (int kt = 0; kt < 2; kt++) {
                int prow = wv * 16 + lm;
                int slot = (kt * 4 + quad + 2 * (lm >> 2)) & 7;       // matches write
                bf16x8 ap = *(const bf16x8*)(lP + prow * 64 + slot * 8);
#pragma unroll
                for (int nt = 0; nt < 8; nt++) {
                    int r = nt * 16 + lm;
                    int c = kt * 4 + quad;
                    int vslot = c ^ (r & 7);
                    bf16x8 bv = *(const bf16x8*)(lV + (r * 8 + vslot) * 8);
                    ao[nt] = __builtin_amdgcn_mfma_f32_16x16x32_bf16(ap, bv, ao[nt], 0, 0, 0);
                }
            }
            __builtin_amdgcn_s_setprio(0);
            // barrier #2: K-next resident for next QK; orders lV/lP reuse.
            asm volatile("s_waitcnt vmcnt(0)" ::: "memory");
            __builtin_amdgcn_s_barrier();
            cur ^= 1;
        }

        // leg epilogue: reduce the per-lane l partials (16-wide), store.
        float* Ob = Opart + (long long)z * 4194304;
#pragma unroll
        for (int r = 0; r < 4; r++) {
            float l = lrow[r];
#pragma unroll
            for (int off = 1; off < 16; off <<= 1) l += __shfl_xor(l, off);
            int sg = qt * 64 + wv * 16 + quad * 4 + r;
#pragma unroll
            for (int nt = 0; nt < 8; nt++) {
                int dg = h * 128 + nt * 16 + lm;
                Ob[(long long)sg * 2048 + dg] = ao[nt][r];
            }
            if (lm == 0) {
                mpart[z * 32768 + h * 2048 + sg] = mrow[r];   // log2 units
                lpart[z * 32768 + h * 2048 + sg] = l;
            }
        }
    }
}

// ---------------------------------------------------------------- combine
// m partials are in log2 units -> exp2f.
__global__ __launch_bounds__(256) void combine_kernel(
    const float* __restrict__ O0, const float* __restrict__ O1,
    const float* __restrict__ mpart, const float* __restrict__ lpart,
    short* __restrict__ attn)
{
    int idx = blockIdx.x * 256 + threadIdx.x;   // 1M threads
    int e = idx * 4;
    int s = e >> 11, h = (e & 2047) >> 7;
    float m0 = mpart[h * 2048 + s], m1 = mpart[32768 + h * 2048 + s];
    float l0 = lpart[h * 2048 + s], l1 = lpart[32768 + h * 2048 + s];
    float M = fmaxf(m0, m1);
    float w0 = exp2f(m0 - M), w1 = exp2f(m1 - M);
    float inv = 1.0f / (l0 * w0 + l1 * w1);
    float4 a = *(const float4*)(O0 + e);
    float4 b = *(const float4*)(O1 + e);
    short4 o;
    o.x = f2bf((a.x * w0 + b.x * w1) * inv);
    o.y = f2bf((a.y * w0 + b.y * w1) * inv);
    o.z = f2bf((a.z * w0 + b.z * w1) * inv);
    o.w = f2bf((a.w * w0 + b.w * w1) * inv);
    *(short4*)(attn + e) = o;
}

// ---------------------------------------------------------------- launch
extern "C" void kernel_launch(void* const* d_in, const int* in_sizes, int n_in,
                              void* d_out, int out_size, void* d_ws, size_t ws_size,
                              hipStream_t stream)
{
    const void* x  = d_in[0];
    const void* wq = d_in[2];
    const void* wk = d_in[3];
    const void* wv = d_in[4];
    const void* wo = d_in[5];

    char* ws = (char*)d_ws;
    size_t off = 0;
    auto alloc = [&](size_t b) { void* p = ws + off; off += (b + 255) & ~(size_t)255; return p; };
    short* wqkv_q = (short*)alloc(25165824);   // [6144][2048] bf16 (q,k,v)
    short* wo_q   = (short*)alloc(8388608);
    float* Opart  = (float*)alloc(33554432);   // [2][2048][2048] fp32
    short* qkv    = (short*)Opart;             // alias: [2048][6144] bf16, dies pre-flash
    short* v_t    = (short*)alloc(8388608);    // [o][t]
    short* q_r    = (short*)alloc(8388608);    // [h][s][128]
    short* k_r    = (short*)alloc(8388608);
    short* attn   = (short*)alloc(8388608);    // [s][2048]
    short* x_bf   = (short*)alloc(8388608);
    float* mpart  = (float*)alloc(262144);     // [2][16][2048]
    float* lpart  = (float*)alloc(262144);
    int*   flag   = (int*)alloc(256);
    if (off > ws_size) return;                 // ~110 MB

    zero_flag<<<1, 64, 0, stream>>>(flag);
    detect_kernel<<<256, 256, 0, stream>>>(
        (const unsigned short*)x, in_sizes[0], flag);

    prep_kernel<<<20480, 256, 0, stream>>>(x, x_bf, wq, wk, wv, wo,
        wqkv_q, wqkv_q + 4194304, wqkv_q + 8388608, wo_q, flag);

    gemm_qkv<<<dim3(32, 16), 256, 0, stream>>>(x_bf, wqkv_q, qkv);

    ropetrans_kernel<<<2048, 256, 0, stream>>>(qkv, q_r, k_r, v_t);

    flash_kernel<<<512, 256, 0, stream>>>(q_r, k_r, v_t, Opart, mpart, lpart);
    combine_kernel<<<4096, 256, 0, stream>>>(
        Opart, Opart + 4194304, mpart, lpart, attn);

    gemm_wo<<<dim3(32, 16), 256, 0, stream>>>(attn, wo_q, (float*)d_out);
}

// Round 12
// 275.129 us; speedup vs baseline: 1.1241x; 1.0676x over previous
//
#include <hip/hip_runtime.h>
#include <cstdint>
#include <cstddef>

// BitLlamaAttention: B=1, S=2048, HIDDEN=2048, NH=16, HD=128, GROUP=128
// r21: r20 base (293.7us), launch-chain + detect slimming only:
//  1) detect samples 1/16 of elements (mechanism is statistical: f32 low
//     halfwords hit exp>=0xF0 at ~1/16 -> flag ~1M; sampled ~65k >> 1000
//     threshold; bf16 ~0). 67MB -> 4MB read.
//  2) zero_flag launch eliminated: detect writes slots[bid]=cnt
//     unconditionally (no zeroing, no atomics, replay-deterministic);
//     prep sums 256 slots in its first wave.
// flash/gemm_qkv/gemm_wo/ropetrans/combine frozen at r20.

typedef __attribute__((ext_vector_type(8))) short bf16x8;
typedef __attribute__((ext_vector_type(4))) float f32x4;
typedef __attribute__((address_space(3))) void lds_void;
typedef const __attribute__((address_space(1))) void gmem_void;

__device__ __forceinline__ short f2bf(float x) {
    union { float f; uint32_t u; } c; c.f = x;
    uint32_t r = (c.u + 0x7FFFu + ((c.u >> 16) & 1u)) >> 16;
    return (short)r;
}
__device__ __forceinline__ float bf2f(short x) {
    union { uint32_t u; float f; } c; c.u = ((uint32_t)(uint16_t)x) << 16;
    return c.f;
}

// ------------------------------------------------------------ dtype probe
// Samples 1/16 of the u16 stream; writes per-block count to slots[bid]
// (unconditional plain store -> no pre-zeroing launch, no atomics).
__global__ __launch_bounds__(256) void detect_kernel(
    const unsigned short* __restrict__ p, int n, int* __restrict__ slots)
{
    int tid = blockIdx.x * 256 + threadIdx.x;
    int cnt = 0;
    for (int i = tid; i < n; i += 1048576) {       // 65536 threads, 1/16 sample
        int e = (p[i] >> 7) & 0xFF;
        cnt += (e >= 0xF0) ? 1 : 0;
    }
#pragma unroll
    for (int off = 1; off < 64; off <<= 1) cnt += __shfl_xor(cnt, off);
    __shared__ int wsum[4];
    if ((threadIdx.x & 63) == 0) wsum[threadIdx.x >> 6] = cnt;
    __syncthreads();
    if (threadIdx.x == 0)
        slots[blockIdx.x] = wsum[0] + wsum[1] + wsum[2] + wsum[3];
}

// ------------------------------------------------- fused convert + quant
// First wave sums the 256 detect slots -> isf32 (threshold 1000).
// bid<4096: canonicalize hidden_states to bf16 (4 elems/thread).
// bid>=4096: ternary groupwise quant of 4 matrices (4 elems/thread,
// group=128 elems=32 lanes, 5-round reduce).
__global__ __launch_bounds__(256) void prep_kernel(
    const void* __restrict__ x, short* __restrict__ x_bf,
    const void* __restrict__ w0, const void* __restrict__ w1,
    const void* __restrict__ w2, const void* __restrict__ w3,
    short* __restrict__ q0, short* __restrict__ q1,
    short* __restrict__ q2, short* __restrict__ q3,
    const int* __restrict__ slots)
{
    __shared__ int sf;
    if (threadIdx.x < 64) {
        int v = 0;
#pragma unroll
        for (int j = 0; j < 4; j++) v += slots[j * 64 + threadIdx.x];
#pragma unroll
        for (int off = 1; off < 64; off <<= 1) v += __shfl_xor(v, off);
        if (threadIdx.x == 0) sf = v;
    }
    __syncthreads();
    bool isf32 = (sf > 1000);

    int bid = blockIdx.x, tid = threadIdx.x;
    if (bid < 4096) {
        int i = (bid * 256 + tid) * 4;
        if (isf32) {
            float4 v = *(const float4*)((const float*)x + i);
            short4 o;
            o.x = f2bf(v.x); o.y = f2bf(v.y); o.z = f2bf(v.z); o.w = f2bf(v.w);
            *(short4*)(x_bf + i) = o;
        } else {
            *(short4*)(x_bf + i) = *(const short4*)((const short*)x + i);
        }
        return;
    }
    int t   = (bid - 4096) * 256 + tid;            // 4M threads
    int mat = t >> 20;
    int e4  = t & 1048575;
    const void* w = (mat == 0) ? w0 : (mat == 1) ? w1 : (mat == 2) ? w2 : w3;
    short*      q = (mat == 0) ? q0 : (mat == 1) ? q1 : (mat == 2) ? q2 : q3;
    float a0, a1, a2, a3;
    if (isf32) {
        float4 v = *(const float4*)((const float*)w + (long long)e4 * 4);
        a0 = v.x; a1 = v.y; a2 = v.z; a3 = v.w;
    } else {
        short4 v = *(const short4*)((const short*)w + (long long)e4 * 4);
        a0 = bf2f(v.x); a1 = bf2f(v.y); a2 = bf2f(v.z); a3 = bf2f(v.w);
    }
    float s = fabsf(a0) + fabsf(a1) + fabsf(a2) + fabsf(a3);
#pragma unroll
    for (int off = 1; off < 32; off <<= 1) s += __shfl_xor(s, off);
    float scale = fmaxf(s * (1.0f / 128.0f), 1e-8f);
    float inv = 1.0f / scale;
    auto qz = [&](float a) -> short {
        float na = a * inv;
        return f2bf((na > 0.5f) ? scale : (na < -0.5f) ? -scale : 0.0f);
    };
    short4 o;
    o.x = qz(a0); o.y = qz(a1); o.z = qz(a2); o.w = qz(a3);
    *(short4*)(q + (long long)e4 * 4) = o;
}

// ---------------------------------------------------------------- QKV GEMM
// C[2048][6144] = x_bf[2048x2048] @ wqkv^T[6144x2048].  128x192 tiles,
// BK=32, grid(32,16) = 512 blocks = 2/CU.  Triple-buffered LDS, 2-deep
// prefetch, counted vmcnt(5).  XCD swizzle: B-locality (3MB B-slice in L2).
__global__ __launch_bounds__(256, 2) void gemm_qkv(
    const short* __restrict__ A, const short* __restrict__ B,
    short* __restrict__ C)
{
    __shared__ short lds[30720];                   // 60 KiB = 3 x (8K A + 12K B)

    int wg = blockIdx.y * 32 + blockIdx.x;         // 512 wgs, 512%8==0
    int sw = (wg & 7) * 64 + (wg >> 3);            // XCD-contiguous chunks
    int bx = sw >> 4, by = sw & 15;                // B-locality: 4 bx/XCD

    const short* Ab = A + (long long)by * 128 * 2048;
    const short* Bb = B + (long long)bx * 192 * 2048;

    int tid = threadIdx.x, lane = tid & 63, wid = tid >> 6;
    int wr = wid >> 1, wc = wid & 1;               // wave grid 2x2
    int quad = lane >> 4, lm = lane & 15;

    f32x4 acc[4][6];
#pragma unroll
    for (int i = 0; i < 4; i++)
#pragma unroll
        for (int j = 0; j < 6; j++)
#pragma unroll
            for (int r = 0; r < 4; r++) acc[i][j][r] = 0.0f;

    auto stage = [&](int tn, short* buf) {
        short* dA = buf;                           // 4096 shorts
        short* dB = buf + 4096;                    // 6144 shorts
#pragma unroll
        for (int l = 0; l < 2; l++) {
            int ci  = l * 256 + tid;               // 512 chunks of 16B
            int row = ci >> 2;
            int kc  = ((ci & 3) - (row >> 1)) & 3; // inverse swizzle on src
            const short* gp = Ab + (long long)row * 2048 + tn * 32 + kc * 8;
            __builtin_amdgcn_global_load_lds((gmem_void*)gp, (lds_void*)(dA + ci * 8), 16, 0, 0);
        }
#pragma unroll
        for (int l = 0; l < 3; l++) {
            int ci  = l * 256 + tid;               // 768 chunks of 16B
            int row = ci >> 2;
            int kc  = ((ci & 3) - (row >> 1)) & 3;
            const short* gp = Bb + (long long)row * 2048 + tn * 32 + kc * 8;
            __builtin_amdgcn_global_load_lds((gmem_void*)gp, (lds_void*)(dB + ci * 8), 16, 0, 0);
        }
    };

    auto tile = [&](short* cur, short* nxt, int tn, bool pf) {
        if (pf) stage(tn, nxt);                    // issue-early prefetch
        short* cA = cur;
        short* cB = cur + 4096;
        bf16x8 af[4], bg[6];
#pragma unroll
        for (int m = 0; m < 4; m++) {
            int R = wr * 64 + m * 16 + lm;
            af[m] = *(const bf16x8*)(cA + R * 32 + (((quad + (R >> 1)) & 3) << 3));
        }
#pragma unroll
        for (int n = 0; n < 3; n++) {
            int R = wc * 96 + n * 16 + lm;
            bg[n] = *(const bf16x8*)(cB + R * 32 + (((quad + (R >> 1)) & 3) << 3));
        }
        __builtin_amdgcn_s_setprio(1);
#pragma unroll
        for (int m = 0; m < 4; m++)
#pragma unroll
            for (int n = 0; n < 3; n++)
                acc[m][n] = __builtin_amdgcn_mfma_f32_16x16x32_bf16(af[m], bg[n], acc[m][n], 0, 0, 0);
        __builtin_amdgcn_s_setprio(0);
#pragma unroll
        for (int n = 3; n < 6; n++) {
            int R = wc * 96 + n * 16 + lm;
            bg[n] = *(const bf16x8*)(cB + R * 32 + (((quad + (R >> 1)) & 3) << 3));
        }
        __builtin_amdgcn_s_setprio(1);
#pragma unroll
        for (int m = 0; m < 4; m++)
#pragma unroll
            for (int n = 3; n < 6; n++)
                acc[m][n] = __builtin_amdgcn_mfma_f32_16x16x32_bf16(af[m], bg[n], acc[m][n], 0, 0, 0);
        __builtin_amdgcn_s_setprio(0);
        if (pf) asm volatile("s_waitcnt vmcnt(5)" ::: "memory");
        else    asm volatile("s_waitcnt vmcnt(0)" ::: "memory");
        __builtin_amdgcn_s_barrier();
    };

    short* c0 = lds;
    short* c1 = lds + 10240;
    short* c2 = lds + 20480;
    stage(0, c0);
    stage(1, c1);
    asm volatile("s_waitcnt vmcnt(5)" ::: "memory");   // tile 0 resident
    __builtin_amdgcn_s_barrier();

    for (int t = 0; t < 64; t++) {
        tile(c0, c2, t + 2, t + 2 < 64);
        short* tmp = c0; c0 = c1; c1 = c2; c2 = tmp;
    }

    // epilogue: row-major bf16
#pragma unroll
    for (int m = 0; m < 4; m++)
#pragma unroll
        for (int n = 0; n < 6; n++)
#pragma unroll
            for (int r = 0; r < 4; r++) {
                int row = by * 128 + wr * 64 + m * 16 + quad * 4 + r;
                int col = bx * 192 + wc * 96 + n * 16 + lm;
                C[(long long)row * 6144 + col] = f2bf(acc[m][n][r]);
            }
}

// --------------------------------------------------- fused RoPE + V-trans
__global__ __launch_bounds__(256) void ropetrans_kernel(
    const short* __restrict__ qkv,
    short* __restrict__ qr, short* __restrict__ kr,
    short* __restrict__ v_t)
{
    __shared__ short lt[4096];
    int bid = blockIdx.x;
    int tid = threadIdx.x;
    if (bid < 1024) {
        const float QSC = 0.1275174150637756f;     // (1/sqrt(128))*log2(e)
        int idx = bid * 256 + tid;
        int d8 = (idx & 7) * 8;
        int h  = (idx >> 3) & 15;
        int s  = idx >> 7;
        long long io = (long long)s * 6144 + h * 128 + d8;
        long long oo = (long long)h * 262144 + (long long)s * 128 + d8;
        bf16x8 x1q = *(const bf16x8*)(qkv + io);
        bf16x8 x2q = *(const bf16x8*)(qkv + io + 64);
        bf16x8 x1k = *(const bf16x8*)(qkv + io + 2048);
        bf16x8 x2k = *(const bf16x8*)(qkv + io + 2112);
        bf16x8 o1q, o2q, o1k, o2k;
#pragma unroll
        for (int j = 0; j < 8; j++) {
            float inv = exp2f((float)(d8 + j) * -0.20762050593261719f);
            float ang = (float)s * inv;
            float sn, c;
            sincosf(ang, &sn, &c);
            float a1 = bf2f(x1q[j]), a2 = bf2f(x2q[j]);
            o1q[j] = f2bf((a1 * c - a2 * sn) * QSC);
            o2q[j] = f2bf((a1 * sn + a2 * c) * QSC);
            float b1 = bf2f(x1k[j]), b2 = bf2f(x2k[j]);
            o1k[j] = f2bf(b1 * c - b2 * sn);
            o2k[j] = f2bf(b1 * sn + b2 * c);
        }
        *(bf16x8*)(qr + oo)      = o1q;
        *(bf16x8*)(qr + oo + 64) = o2q;
        *(bf16x8*)(kr + oo)      = o1k;
        *(bf16x8*)(kr + oo + 64) = o2k;
    } else {
        int bt = (bid - 1024) & 31, bo = (bid - 1024) >> 5;
        int r = tid >> 3, c = tid & 7;
#pragma unroll
        for (int h = 0; h < 2; h++) {
            int row = h * 32 + r;                  // t-local
            bf16x8 v = *(const bf16x8*)(qkv + (long long)(bt * 64 + row) * 6144 + 4096 + bo * 64 + c * 8);
            *(bf16x8*)(lt + row * 64 + ((c ^ (row & 7)) << 3)) = v;
        }
        __syncthreads();
#pragma unroll
        for (int h = 0; h < 2; h++) {
            int o = h * 32 + r;                    // o-local
            bf16x8 ov;
#pragma unroll
            for (int k = 0; k < 8; k++) {
                int row = c * 8 + k;
                ov[k] = lt[row * 64 + ((((o >> 3) ^ (row & 7))) << 3) + (o & 7)];
            }
            *(bf16x8*)(v_t + (long long)(bo * 64 + o) * 2048 + bt * 64 + c * 8) = ov;
        }
    }
}

// ---------------------------------------------------------------- WO GEMM
// d_out[2048][2048] fp32 = attn bf16 @ wo_q^T.  128x64 tiles, BK=32,
// grid(32,16) = 512 = 2/CU.  Triple-buffered LDS, counted vmcnt(3).
// XCD swizzle: B-locality (1MB B-slice/XCD in L2).
__global__ __launch_bounds__(256, 2) void gemm_wo(
    const short* __restrict__ A, const short* __restrict__ B,
    float* __restrict__ C)
{
    __shared__ short lds[18432];                   // 36 KiB = 3 x (8K A + 4K B)

    int wg = blockIdx.y * 32 + blockIdx.x;         // 512 wgs
    int sw = (wg & 7) * 64 + (wg >> 3);            // XCD-contiguous
    int bx = sw >> 4, by = sw & 15;                // B-locality: 4 bx/XCD

    const short* Ab = A + (long long)by * 128 * 2048;
    const short* Bb = B + (long long)bx * 64 * 2048;

    int tid = threadIdx.x, lane = tid & 63, wid = tid >> 6;
    int wr = wid >> 1, wc = wid & 1;               // wave grid 2x2
    int quad = lane >> 4, lm = lane & 15;

    f32x4 acc[4][2];
#pragma unroll
    for (int i = 0; i < 4; i++)
#pragma unroll
        for (int j = 0; j < 2; j++)
#pragma unroll
            for (int r = 0; r < 4; r++) acc[i][j][r] = 0.0f;

    auto stage = [&](int tn, short* buf) {
        short* dA = buf;                           // 4096 shorts (512 chunks)
        short* dB = buf + 4096;                    // 2048 shorts (256 chunks)
#pragma unroll
        for (int l = 0; l < 2; l++) {
            int ci  = l * 256 + tid;
            int row = ci >> 2;
            int kc  = ((ci & 3) - (row >> 1)) & 3;
            const short* gp = Ab + (long long)row * 2048 + tn * 32 + kc * 8;
            __builtin_amdgcn_global_load_lds((gmem_void*)gp, (lds_void*)(dA + ci * 8), 16, 0, 0);
        }
        {
            int ci  = tid;
            int row = ci >> 2;
            int kc  = ((ci & 3) - (row >> 1)) & 3;
            const short* gp = Bb + (long long)row * 2048 + tn * 32 + kc * 8;
            __builtin_amdgcn_global_load_lds((gmem_void*)gp, (lds_void*)(dB + ci * 8), 16, 0, 0);
        }
    };

    auto tile = [&](short* cur, short* nxt, int tn, bool pf) {
        if (pf) stage(tn, nxt);
        short* cA = cur;
        short* cB = cur + 4096;
        bf16x8 af[4], bg[2];
#pragma unroll
        for (int m = 0; m < 4; m++) {
            int R = wr * 64 + m * 16 + lm;
            af[m] = *(const bf16x8*)(cA + R * 32 + (((quad + (R >> 1)) & 3) << 3));
        }
#pragma unroll
        for (int n = 0; n < 2; n++) {
            int R = wc * 32 + n * 16 + lm;
            bg[n] = *(const bf16x8*)(cB + R * 32 + (((quad + (R >> 1)) & 3) << 3));
        }
        __builtin_amdgcn_s_setprio(1);
#pragma unroll
        for (int m = 0; m < 4; m++)
#pragma unroll
            for (int n = 0; n < 2; n++)
                acc[m][n] = __builtin_amdgcn_mfma_f32_16x16x32_bf16(af[m], bg[n], acc[m][n], 0, 0, 0);
        __builtin_amdgcn_s_setprio(0);
        if (pf) asm volatile("s_waitcnt vmcnt(3)" ::: "memory");
        else    asm volatile("s_waitcnt vmcnt(0)" ::: "memory");
        __builtin_amdgcn_s_barrier();
    };

    short* c0 = lds;
    short* c1 = lds + 6144;
    short* c2 = lds + 12288;
    stage(0, c0);
    stage(1, c1);
    asm volatile("s_waitcnt vmcnt(3)" ::: "memory");
    __builtin_amdgcn_s_barrier();

    for (int t = 0; t < 64; t++) {
        tile(c0, c2, t + 2, t + 2 < 64);
        short* tmp = c0; c0 = c1; c1 = c2; c2 = tmp;
    }

    // epilogue: fp32 row-major
#pragma unroll
    for (int m = 0; m < 4; m++)
#pragma unroll
        for (int n = 0; n < 2; n++)
#pragma unroll
            for (int r = 0; r < 4; r++) {
                int row = by * 128 + wr * 64 + m * 16 + quad * 4 + r;
                int col = bx * 64 + wc * 32 + n * 16 + lm;
                C[(long long)row * 2048 + col] = acc[m][n][r];
            }
}

// ---------------------------------------------------------------- flash attn
// 512 blocks: pair p = bid>>5, h = (bid>>1)&15, z = bid&1 j-half.  Legs
// qt=31-p then qt=p.  Counted-vmcnt pipeline: lK double-buffered; V[jt] +
// K[jt+1] issued at loop top; barrier#1 = vmcnt(4) lgkmcnt(0) (V + lP
// resident, K-next in flight ACROSS the barrier); barrier#2 = vmcnt(0)
// with the whole iteration behind it.  Scores in log2 units; per-lane
// partial l; vote-gated max (THR=11.5); setprio on MFMA clusters.
__global__ __launch_bounds__(256) void flash_kernel(
    const short* __restrict__ q_r, const short* __restrict__ k_r,
    const short* __restrict__ v_t, float* __restrict__ Opart,
    float* __restrict__ mpart, float* __restrict__ lpart)
{
    const float THR = 11.5f;                       // ~8 nats in log2 units
    int bid = blockIdx.x;
    int p = bid >> 5;
    int h = (bid >> 1) & 15;
    int z = bid & 1;

    int tid = threadIdx.x, lane = tid & 63, wv = tid >> 6;
    int quad = lane >> 4, lm = lane & 15;

    __shared__ short lK[2][64 * 128];              // double-buffered
    __shared__ short lV[128 * 64];
    __shared__ short lP[64 * 64];

    const short* kb = k_r + h * 262144;
    const short* vb = v_t + h * 128 * 2048;

    auto stageK = [&](int jtgt, short* dst) {
#pragma unroll
        for (int i = 0; i < 4; i++) {
            int ci = i * 256 + tid;
            int r = ci >> 4, cp = ci & 15;
            int c = (cp & 8) | ((cp & 7) ^ (r & 7));
            const short* gp = kb + (jtgt * 64 + r) * 128 + c * 8;
            __builtin_amdgcn_global_load_lds((gmem_void*)gp, (lds_void*)(dst + ci * 8), 16, 0, 0);
        }
    };
    auto stageV = [&](int jtgt) {
#pragma unroll
        for (int i = 0; i < 4; i++) {
            int ci = i * 256 + tid;
            int r = ci >> 3, cp = ci & 7;
            int c = cp ^ (r & 7);
            const short* gp = vb + r * 2048 + jtgt * 64 + c * 8;
            __builtin_amdgcn_global_load_lds((gmem_void*)gp, (lds_void*)(lV + ci * 8), 16, 0, 0);
        }
    };

    for (int leg = 0; leg < 2; leg++) {
        int qt = leg ? p : 31 - p;
        int n  = qt + 1;
        int jhalf = (n + 1) >> 1;
        int jb = z ? jhalf : 0;
        int je = z ? n : jhalf;

        const short* qb = q_r + h * 262144 + (qt * 64 + wv * 16) * 128;
        bf16x8 aq[4];
#pragma unroll
        for (int kc = 0; kc < 4; kc++)
            aq[kc] = *(const bf16x8*)(qb + lm * 128 + kc * 32 + quad * 8);

        f32x4 ao[8];
#pragma unroll
        for (int nt = 0; nt < 8; nt++)
#pragma unroll
            for (int r = 0; r < 4; r++) ao[nt][r] = 0.0f;
        float mrow[4], lrow[4];                    // lrow = PER-LANE partial
#pragma unroll
        for (int r = 0; r < 4; r++) { mrow[r] = -1e30f; lrow[r] = 0.0f; }

        int cur = 0;
        if (jb < je) stageK(jb, lK[0]);
        asm volatile("s_waitcnt vmcnt(0)" ::: "memory");
        __builtin_amdgcn_s_barrier();

        for (int jt = jb; jt < je; jt++) {
            bool pk = (jt + 1 < je);
            stageV(jt);                            // 4 loads
            if (pk) stageK(jt + 1, lK[cur ^ 1]);   // 4 loads, cross-barrier
            f32x4 as[4];
#pragma unroll
            for (int nt = 0; nt < 4; nt++)
#pragma unroll
                for (int r = 0; r < 4; r++) as[nt][r] = 0.0f;
            __builtin_amdgcn_s_setprio(1);
#pragma unroll
            for (int kc = 0; kc < 4; kc++) {
#pragma unroll
                for (int nt = 0; nt < 4; nt++) {
                    int r = nt * 16 + lm;
                    int c = kc * 4 + quad;
                    int slot = (c & 8) | ((c & 7) ^ (r & 7));
                    bf16x8 bk = *(const bf16x8*)(lK[cur] + (r * 16 + slot) * 8);
                    as[nt] = __builtin_amdgcn_mfma_f32_16x16x32_bf16(aq[kc], bk, as[nt], 0, 0, 0);
                }
            }
            __builtin_amdgcn_s_setprio(0);
            if (jt == qt) {                        // diag mask only
#pragma unroll
                for (int nt = 0; nt < 4; nt++)
#pragma unroll
                    for (int r = 0; r < 4; r++) {
                        int qg = wv * 16 + quad * 4 + r;
                        int tg = nt * 16 + lm;
                        if (tg > qg) as[nt][r] = -1e30f;
                    }
            }
#pragma unroll
            for (int r = 0; r < 4; r++) {
                float lmax = fmaxf(fmaxf(as[0][r], as[1][r]), fmaxf(as[2][r], as[3][r]));
                if (__any(lmax > mrow[r] + THR)) {
                    float mx = lmax;
#pragma unroll
                    for (int off = 1; off < 16; off <<= 1) mx = fmaxf(mx, __shfl_xor(mx, off));
                    if (mx > mrow[r] + THR) {
                        float alpha = exp2f(mrow[r] - mx);   // group-uniform
                        lrow[r] *= alpha;
#pragma unroll
                        for (int nt = 0; nt < 8; nt++) ao[nt][r] *= alpha;
                        mrow[r] = mx;
                    }
                }
                float ps = 0.0f;
#pragma unroll
                for (int nt = 0; nt < 4; nt++) {
                    float pv = exp2f(as[nt][r] - mrow[r]);
                    as[nt][r] = pv;
                    ps += pv;
                }
                lrow[r] += ps;                     // per-lane partial
                int row = wv * 16 + quad * 4 + r;
#pragma unroll
                for (int nt = 0; nt < 4; nt++) {
                    int slot = (nt * 2 + (lm >> 3) + 2 * quad) & 7;   // uniform
                    lP[row * 64 + slot * 8 + (lm & 7)] = f2bf(as[nt][r]);
                }
            }
            // barrier #1: V (oldest 4 loads) + lP must be resident.
            // K-next (newest 4) stays IN FLIGHT across the barrier.
            if (pk) asm volatile("s_waitcnt vmcnt(4) lgkmcnt(0)" ::: "memory");
            else    asm volatile("s_waitcnt vmcnt(0) lgkmcnt(0)" ::: "memory");
            __builtin_amdgcn_s_barrier();
            __builtin_amdgcn_s_setprio(1);
#pragma unroll
            for (int kt = 0; kt < 2; kt++) {
                int prow = wv * 16 + lm;
                int slot = (kt * 4 + quad + 2 * (lm >> 2)) & 7;       // matches write
                bf16x8 ap = *(const bf16x8*)(lP + prow * 64 + slot * 8);
#pragma unroll
                for (int nt = 0; nt < 8; nt++) {
                    int r = nt * 16 + lm;
                    int c = kt * 4 + quad;
                    int vslot = c ^ (r & 7);
                    bf16x8 bv = *(const bf16x8*)(lV + (r * 8 + vslot) * 8);
                    ao[nt] = __builtin_amdgcn_mfma_f32_16x16x32_bf16(ap, bv, ao[nt], 0, 0, 0);
                }
            }
            __builtin_amdgcn_s_setprio(0);
            // barrier #2: K-next resident for next QK; orders lV/lP reuse.
            asm volatile("s_waitcnt vmcnt(0)" ::: "memory");
            __builtin_amdgcn_s_barrier();
            cur ^= 1;
        }

        // leg epilogue: reduce the per-lane l partials (16-wide), store.
        float* Ob = Opart + (long long)z * 4194304;
#pragma unroll
        for (int r = 0; r < 4; r++) {
            float l = lrow[r];
#pragma unroll
            for (int off = 1; off < 16; off <<= 1) l += __shfl_xor(l, off);
            int sg = qt * 64 + wv * 16 + quad * 4 + r;
#pragma unroll
            for (int nt = 0; nt < 8; nt++) {
                int dg = h * 128 + nt * 16 + lm;
                Ob[(long long)sg * 2048 + dg] = ao[nt][r];
            }
            if (lm == 0) {
                mpart[z * 32768 + h * 2048 + sg] = mrow[r];   // log2 units
                lpart[z * 32768 + h * 2048 + sg] = l;
            }
        }
    }
}

// ---------------------------------------------------------------- combine
// m partials are in log2 units -> exp2f.
__global__ __launch_bounds__(256) void combine_kernel(
    const float* __restrict__ O0, const float* __restrict__ O1,
    const float* __restrict__ mpart, const float* __restrict__ lpart,
    short* __restrict__ attn)
{
    int idx = blockIdx.x * 256 + threadIdx.x;   // 1M threads
    int e = idx * 4;
    int s = e >> 11, h = (e & 2047) >> 7;
    float m0 = mpart[h * 2048 + s], m1 = mpart[32768 + h * 2048 + s];
    float l0 = lpart[h * 2048 + s], l1 = lpart[32768 + h * 2048 + s];
    float M = fmaxf(m0, m1);
    float w0 = exp2f(m0 - M), w1 = exp2f(m1 - M);
    float inv = 1.0f / (l0 * w0 + l1 * w1);
    float4 a = *(const float4*)(O0 + e);
    float4 b = *(const float4*)(O1 + e);
    short4 o;
    o.x = f2bf((a.x * w0 + b.x * w1) * inv);
    o.y = f2bf((a.y * w0 + b.y * w1) * inv);
    o.z = f2bf((a.z * w0 + b.z * w1) * inv);
    o.w = f2bf((a.w * w0 + b.w * w1) * inv);
    *(short4*)(attn + e) = o;
}

// ---------------------------------------------------------------- launch
extern "C" void kernel_launch(void* const* d_in, const int* in_sizes, int n_in,
                              void* d_out, int out_size, void* d_ws, size_t ws_size,
                              hipStream_t stream)
{
    const void* x  = d_in[0];
    const void* wq = d_in[2];
    const void* wk = d_in[3];
    const void* wv = d_in[4];
    const void* wo = d_in[5];

    char* ws = (char*)d_ws;
    size_t off = 0;
    auto alloc = [&](size_t b) { void* p = ws + off; off += (b + 255) & ~(size_t)255; return p; };
    short* wqkv_q = (short*)alloc(25165824);   // [6144][2048] bf16 (q,k,v)
    short* wo_q   = (short*)alloc(8388608);
    float* Opart  = (float*)alloc(33554432);   // [2][2048][2048] fp32
    short* qkv    = (short*)Opart;             // alias: [2048][6144] bf16, dies pre-flash
    short* v_t    = (short*)alloc(8388608);    // [o][t]
    short* q_r    = (short*)alloc(8388608);    // [h][s][128]
    short* k_r    = (short*)alloc(8388608);
    short* attn   = (short*)alloc(8388608);    // [s][2048]
    short* x_bf   = (short*)alloc(8388608);
    float* mpart  = (float*)alloc(262144);     // [2][16][2048]
    float* lpart  = (float*)alloc(262144);
    int*   slots  = (int*)alloc(1024);         // [256] per-block detect counts
    if (off > ws_size) return;                 // ~110 MB

    detect_kernel<<<256, 256, 0, stream>>>(
        (const unsigned short*)x, in_sizes[0], slots);

    prep_kernel<<<20480, 256, 0, stream>>>(x, x_bf, wq, wk, wv, wo,
        wqkv_q, wqkv_q + 4194304, wqkv_q + 8388608, wo_q, slots);

    gemm_qkv<<<dim3(32, 16), 256, 0, stream>>>(x_bf, wqkv_q, qkv);

    ropetrans_kernel<<<2048, 256, 0, stream>>>(qkv, q_r, k_r, v_t);

    flash_kernel<<<512, 256, 0, stream>>>(q_r, k_r, v_t, Opart, mpart, lpart);
    combine_kernel<<<4096, 256, 0, stream>>>(
        Opart, Opart + 4194304, mpart, lpart, attn);

    gemm_wo<<<dim3(32, 16), 256, 0, stream>>>(attn, wo_q, (float*)d_out);
}